// Round 14
// baseline (224.890 us; speedup 1.0000x reference)
//
#include <hip/hip_runtime.h>
#include <hip/hip_fp16.h>
#include <math.h>

#define NN 100000
#define NE 1600000
#define HID 64
// fine buckets (binB granularity)
#define BN 128
#define NBUCK 782          // ceil(NN/128)
#define FBCAP 2304         // fine bucket capacity (mean 2048, +5.7 sigma)
// coarse superbuckets (binA granularity)
#define NSB 49             // ceil(NN/2048)
#define SBCAP 34816        // superbucket capacity (mean 32653, +12 sigma)
#define CHUNK1 2048
#define NBLK1 782          // ceil(NE/2048)
#define NSLICE 16          // binA2 slices per superbucket
#define SLCAP 2304         // >= ceil(SBCAP/16) = 2176
#define CSTRIDE 32         // ints between cursors (128 B)
#define XPITCH 136         // LDS row pitch in halfs (128 + 8; 272 B, 16B-aligned rows)

typedef _Float16 half8 __attribute__((ext_vector_type(8)));
typedef float floatx4 __attribute__((ext_vector_type(4)));

__device__ __forceinline__ __half2 shfl_xor_h2(__half2 v, int m) {
    unsigned int u = *(unsigned int*)&v;
    u = __shfl_xor(u, m);
    return *(__half2*)&u;
}
__device__ __forceinline__ unsigned int h2bits(__half2 v) {
    return *(unsigned int*)&v;
}

// ---------------- CSR build: two-level multisplit ----------------

// Pass A1: multisplit edges into 49 superbuckets (dst>>11). 2048-edge chunks,
// 782 blocks (~3/CU). Packed u32: src (17b) | (dst & 2047) << 17.
__global__ __launch_bounds__(256) void k_binA1(const int* __restrict__ src,
                                               const int* __restrict__ dst,
                                               int* __restrict__ bcur1,
                                               unsigned int* __restrict__ sbdata) {
    __shared__ unsigned int par[CHUNK1];      // 8 KB
    __shared__ unsigned short rnk[CHUNK1];    // 4 KB
    __shared__ unsigned char bkt[CHUNK1];     // 2 KB
    __shared__ int hist[NSB];
    __shared__ int base[NSB];
    int tid = threadIdx.x;
    int e0 = blockIdx.x * CHUNK1;
    int m = NE - e0; if (m > CHUNK1) m = CHUNK1;
    if (tid < NSB) hist[tid] = 0;
    __syncthreads();
    for (int i = tid; i < m; i += 256) {
        int s = src[e0 + i], d = dst[e0 + i];
        int b = d >> 11;
        par[i] = (unsigned int)s | ((unsigned int)(d & 2047) << 17);
        bkt[i] = (unsigned char)b;
        rnk[i] = (unsigned short)atomicAdd(&hist[b], 1);
    }
    __syncthreads();
    if (tid < NSB) {
        int h = hist[tid];
        base[tid] = h ? atomicAdd(&bcur1[tid * CSTRIDE], h) : 0;
    }
    __syncthreads();
    for (int i = tid; i < m; i += 256) {
        int b = bkt[i];
        int pos = base[b] + rnk[i];
        if (pos < SBCAP) sbdata[(size_t)b * SBCAP + pos] = par[i];
    }
}

// Pass A2: split each superbucket into its 16 fine buckets (16 slices each ->
// 784 blocks). Output u32: src (17b) | dlocal(7b) << 17.
__global__ __launch_bounds__(256) void k_binA2(const int* __restrict__ bcur1,
                                               const unsigned int* __restrict__ sbdata,
                                               int* __restrict__ bcur2,
                                               unsigned int* __restrict__ fbdata) {
    __shared__ unsigned int par[SLCAP];       // 9.2 KB
    __shared__ unsigned short rnk[SLCAP];     // 4.6 KB
    __shared__ unsigned char bkt[SLCAP];      // 2.3 KB
    __shared__ int hist[16];
    __shared__ int base[16];
    int tid = threadIdx.x;
    int sb = blockIdx.x >> 4, sl = blockIdx.x & 15;
    int m = bcur1[sb * CSTRIDE]; if (m > SBCAP) m = SBCAP;
    int L = (m + NSLICE - 1) >> 4;
    int lo = sl * L;
    int cnt = m - lo; if (cnt > L) cnt = L; if (cnt < 0) cnt = 0;
    if (tid < 16) hist[tid] = 0;
    __syncthreads();
    const unsigned int* sp = sbdata + (size_t)sb * SBCAP + lo;
    for (int i = tid; i < cnt; i += 256) {
        unsigned int u = sp[i];
        int dlow = (u >> 17) & 2047;
        int f = dlow >> 7;
        par[i] = (u & 0x1ffffu) | ((unsigned int)(dlow & 127) << 17);
        bkt[i] = (unsigned char)f;
        rnk[i] = (unsigned short)atomicAdd(&hist[f], 1);
    }
    __syncthreads();
    if (tid < 16) {
        int h = hist[tid];
        base[tid] = h ? atomicAdd(&bcur2[(sb * 16 + tid) * CSTRIDE], h) : 0;
    }
    __syncthreads();
    for (int i = tid; i < cnt; i += 256) {
        int f = bkt[i];
        int pos = base[f] + rnk[i];
        if (pos < FBCAP) fbdata[(size_t)(sb * 16 + f) * FBCAP + pos] = par[i];
    }
}

// exclusive scan of fine-bucket totals — wave-level scan (2 barriers).
__global__ void k_bscan(const int* __restrict__ bcur2, int* __restrict__ ebase) {
    __shared__ int ls[16];
    int t = threadIdx.x;
    int lane = t & 63, wid = t >> 6;
    int v = 0;
    if (t < NBUCK) {
        int m = bcur2[t * CSTRIDE];
        v = (m < FBCAP) ? m : FBCAP;
    }
    int orig = v;
    for (int off = 1; off < 64; off <<= 1) {
        int u = __shfl_up(v, off);
        if (lane >= off) v += u;
    }
    if (lane == 63) ls[wid] = v;
    __syncthreads();
    if (wid == 0) {
        int w = (lane < 16) ? ls[lane] : 0;
        for (int off = 1; off < 16; off <<= 1) {
            int u = __shfl_up(w, off);
            if (lane >= off) w += u;
        }
        if (lane < 16) ls[lane] = w;
    }
    __syncthreads();
    int base = wid ? ls[wid - 1] : 0;
    int incl = base + v;
    if (t < NBUCK) ebase[t] = incl - orig;
    if (t == NBUCK - 1) ebase[NBUCK] = incl;  // = NE
}

// Pass B: per fine bucket (256 threads) — stage edges in LDS, count per node,
// dinv, rp, then scatter perm within the bucket's contiguous span (L2-local).
__global__ __launch_bounds__(256) void k_binB(const int* __restrict__ bcur2,
                                              const int* __restrict__ ebase,
                                              const unsigned int* __restrict__ fbdata,
                                              int* __restrict__ rp, float* __restrict__ dinv,
                                              int* __restrict__ perm) {
    __shared__ unsigned int se[FBCAP];
    __shared__ int cnt[BN];
    __shared__ int scn[BN];
    int b = blockIdx.x, tid = threadIdx.x;
    int m = bcur2[b * CSTRIDE]; if (m > FBCAP) m = FBCAP;
    int base = ebase[b];
    for (int i = tid; i < m; i += 256) se[i] = fbdata[(size_t)b * FBCAP + i];
    if (tid < BN) cnt[tid] = 0;
    __syncthreads();
    for (int i = tid; i < m; i += 256) atomicAdd(&cnt[se[i] >> 17], 1);
    __syncthreads();
    int c = (tid < BN) ? cnt[tid] : 0;
    int g = b * BN + tid;
    if (tid < BN && g < NN) dinv[g] = (c > 0) ? rsqrtf((float)c) : 0.0f;
    if (tid < BN) scn[tid] = c;
    __syncthreads();
    for (int off = 1; off < BN; off <<= 1) {
        int u = (tid >= off && tid < BN) ? scn[tid - off] : 0;
        __syncthreads();
        if (tid < BN) scn[tid] += u;
        __syncthreads();
    }
    if (tid < BN) {
        int excl = scn[tid] - c;
        if (g < NN) rp[g] = base + excl;
        cnt[tid] = excl;  // reuse as running cursor
    }
    if (b == NBUCK - 1 && tid == 0) rp[NN] = ebase[NBUCK];
    __syncthreads();
    for (int i = tid; i < m; i += 256) {
        unsigned int u = se[i];
        int pos = atomicAdd(&cnt[u >> 17], 1);
        perm[base + pos] = (int)(u & 0x1ffffu);
    }
}

// ---------------- layer 1 fused: aggregate x + dense1 -> fp16 th ----------------

__global__ __launch_bounds__(256) void k_l1f(
        const int* __restrict__ rp, const int* __restrict__ perm,
        const float* __restrict__ dinv, const float* __restrict__ x,
        const float* __restrict__ W, const float* __restrict__ V,
        const float* __restrict__ b, unsigned short* __restrict__ th, int N) {
    __shared__ float sW[640], sV[640];
    for (int i = threadIdx.x; i < 640; i += 256) { sW[i] = W[i]; sV[i] = V[i]; }
    __syncthreads();
    int n = (blockIdx.x * 256 + threadIdx.x) >> 4;
    if (n >= N) return;
    int sub = threadIdx.x & 15;
    int beg = rp[n], end = rp[n + 1];
    float ag[10];
#pragma unroll
    for (int k = 0; k < 10; ++k) ag[k] = 0.0f;
    for (int j = beg + sub; j < end; j += 16) {
        int s = perm[j];
        float w = dinv[s];
        const float2* xr = (const float2*)(x + (size_t)s * 10);
        float2 v0 = xr[0], v1 = xr[1], v2 = xr[2], v3 = xr[3], v4 = xr[4];
        ag[0] += w * v0.x; ag[1] += w * v0.y; ag[2] += w * v1.x; ag[3] += w * v1.y;
        ag[4] += w * v2.x; ag[5] += w * v2.y; ag[6] += w * v3.x; ag[7] += w * v3.y;
        ag[8] += w * v4.x; ag[9] += w * v4.y;
    }
#pragma unroll
    for (int mk = 1; mk <= 8; mk <<= 1) {
#pragma unroll
        for (int k = 0; k < 10; ++k) ag[k] += __shfl_xor(ag[k], mk);
    }
    float dn = dinv[n];
#pragma unroll
    for (int k = 0; k < 10; ++k) ag[k] *= dn;
    const float2* xn = (const float2*)(x + (size_t)n * 10);
    float2 x0 = xn[0], x1 = xn[1], x2 = xn[2], x3 = xn[3], x4 = xn[4];
    float xv[10] = {x0.x, x0.y, x1.x, x1.y, x2.x, x2.y, x3.x, x3.y, x4.x, x4.y};
    int f0 = sub * 4;
    float4 bb = *(const float4*)(b + f0);
    float acc[4] = {bb.x, bb.y, bb.z, bb.w};
#pragma unroll
    for (int k = 0; k < 10; ++k) {
        float4 wq = *(const float4*)&sW[k * HID + f0];
        float4 vq = *(const float4*)&sV[k * HID + f0];
        acc[0] += ag[k] * wq.x + xv[k] * vq.x;
        acc[1] += ag[k] * wq.y + xv[k] * vq.y;
        acc[2] += ag[k] * wq.z + xv[k] * vq.z;
        acc[3] += ag[k] * wq.w + xv[k] * vq.w;
    }
    __half2 lo = __floats2half2_rn(fmaxf(acc[0], 0.0f), fmaxf(acc[1], 0.0f));
    __half2 hi = __floats2half2_rn(fmaxf(acc[2], 0.0f), fmaxf(acc[3], 0.0f));
    *(uint2*)(th + (size_t)n * HID + f0) = make_uint2(h2bits(lo), h2bits(hi));
}

// ---------------- layer-2 aggregation (gather, fp16 packed math) ----------------

__global__ __launch_bounds__(256) void k_agg64h(
        const int* __restrict__ rp, const int* __restrict__ perm,
        const float* __restrict__ dinv, const unsigned short* __restrict__ th,
        unsigned short* __restrict__ aggth, int N) {
    int wid = (blockIdx.x * blockDim.x + threadIdx.x) >> 6;
    if (wid >= N) return;
    int n = __builtin_amdgcn_readfirstlane(wid);
    int lane = threadIdx.x & 63;
    int grp = lane >> 3;
    int sub = lane & 7;
    int beg = rp[n], end = rp[n + 1];
    __half2 a0 = __float2half2_rn(0.0f), a1 = a0, a2 = a0, a3 = a0;
    for (int j = beg + grp; j < end; j += 8) {
        int s = perm[j];
        __half2 w2 = __float2half2_rn(dinv[s]);
        uint4 u = *(const uint4*)(th + (size_t)s * HID + sub * 8);
        a0 = __hfma2(w2, *(__half2*)&u.x, a0);
        a1 = __hfma2(w2, *(__half2*)&u.y, a1);
        a2 = __hfma2(w2, *(__half2*)&u.z, a2);
        a3 = __hfma2(w2, *(__half2*)&u.w, a3);
    }
#pragma unroll
    for (int m = 8; m < 64; m <<= 1) {
        a0 = __hadd2(a0, shfl_xor_h2(a0, m));
        a1 = __hadd2(a1, shfl_xor_h2(a1, m));
        a2 = __hadd2(a2, shfl_xor_h2(a2, m));
        a3 = __hadd2(a3, shfl_xor_h2(a3, m));
    }
    if (grp == 0) {
        __half2 dn2 = __float2half2_rn(dinv[n]);
        uint4 o;
        o.x = h2bits(__hmul2(dn2, a0));
        o.y = h2bits(__hmul2(dn2, a1));
        o.z = h2bits(__hmul2(dn2, a2));
        o.w = h2bits(__hmul2(dn2, a3));
        *(uint4*)(aggth + (size_t)n * HID + sub * 8) = o;
    }
}

// layer-3 aggregation + log_softmax: 16 lanes per node, lane-per-edge.
__global__ __launch_bounds__(256) void k_agg3lsm(const int* __restrict__ rp,
                                                 const int* __restrict__ perm,
                                                 const float* __restrict__ dinv,
                                                 const float2* __restrict__ h3,
                                                 const float2* __restrict__ y3,
                                                 float* __restrict__ out, int N) {
    int n = (blockIdx.x * 256 + threadIdx.x) >> 4;
    if (n >= N) return;
    int sl = threadIdx.x & 15;
    int beg = rp[n], end = rp[n + 1];
    float a0 = 0.0f, a1 = 0.0f;
    for (int j = beg + sl; j < end; j += 16) {
        int s = perm[j];
        float w = dinv[s];
        float2 hh = h3[s];
        a0 += w * hh.x;
        a1 += w * hh.y;
    }
#pragma unroll
    for (int mk = 1; mk <= 8; mk <<= 1) {
        a0 += __shfl_xor(a0, mk);
        a1 += __shfl_xor(a1, mk);
    }
    if (sl == 0) {
        float dn = dinv[n];
        float2 yy = y3[n];
        float z0 = dn * a0 + yy.x;
        float z1 = dn * a1 + yy.y;
        float m = fmaxf(z0, z1);
        float l = m + logf(expf(z0 - m) + expf(z1 - m));
        out[n * 2 + 0] = z0 - l;
        out[n * 2 + 1] = z1 - l;
    }
}

// ---------------- fused dense 2+3 via MFMA ----------------

__global__ __launch_bounds__(256) void k_dense23m(
        const unsigned short* __restrict__ aggth, const unsigned short* __restrict__ th,
        const float* __restrict__ W, const float* __restrict__ V,
        const float* __restrict__ b, const float* __restrict__ W3,
        const float* __restrict__ V3, const float* __restrict__ b3,
        float2* __restrict__ h3, float2* __restrict__ y3, int N) {
    __shared__ _Float16 sX[64 * XPITCH];    // [node][K]  K: 0..63 aggth, 64..127 th
    __shared__ _Float16 sWT[64 * XPITCH];   // [feat][K]  K: 0..63 W2,   64..127 V2
    __shared__ float sB2[64];
    __shared__ float sW3[128], sV3[128];
    int tid = threadIdx.x;
    int base = blockIdx.x * 64;
    {
        int f = tid & 63;
        int g = tid >> 6;                      // 0..3
        const float* Wsrc = (g < 2) ? W : V;
        int kbase = (g & 1) * 32;
        int Kbase = (g < 2) ? kbase : (64 + kbase);
#pragma unroll
        for (int k2 = 0; k2 < 32; k2 += 2) {
            float w0 = Wsrc[(kbase + k2) * 64 + f];
            float w1 = Wsrc[(kbase + k2 + 1) * 64 + f];
            __half2 h = __floats2half2_rn(w0, w1);
            *(unsigned int*)&sWT[f * XPITCH + Kbase + k2] = h2bits(h);
        }
        if (tid < 64) sB2[tid] = b[tid];
        if (tid < 128) { sW3[tid] = W3[tid]; sV3[tid] = V3[tid]; }
    }
    {
        int n = tid >> 2, p = tid & 3;
        int g = base + n;
        uint4 z = make_uint4(0, 0, 0, 0);
        uint4 a0 = z, a1 = z, c0 = z, c1 = z;
        if (g < N) {
            const uint4* ap = (const uint4*)(aggth + (size_t)g * HID + p * 16);
            const uint4* cp = (const uint4*)(th + (size_t)g * HID + p * 16);
            a0 = ap[0]; a1 = ap[1];
            c0 = cp[0]; c1 = cp[1];
        }
        *(uint4*)&sX[n * XPITCH + p * 16] = a0;
        *(uint4*)&sX[n * XPITCH + p * 16 + 8] = a1;
        *(uint4*)&sX[n * XPITCH + 64 + p * 16] = c0;
        *(uint4*)&sX[n * XPITCH + 64 + p * 16 + 8] = c1;
    }
    __syncthreads();
    int lane = tid & 63;
    int wv = tid >> 6;          // wave id: rows wv*16 .. wv*16+15
    int ml = lane & 15, quad = lane >> 4;
    half8 a[4];
#pragma unroll
    for (int kt = 0; kt < 4; ++kt)
        a[kt] = *(const half8*)&sX[(wv * 16 + ml) * XPITCH + kt * 32 + quad * 8];
    float p0[4] = {}, p1[4] = {}, q0[4] = {}, q1[4] = {};
#pragma unroll
    for (int c = 0; c < 4; ++c) {
        floatx4 acc = {0.0f, 0.0f, 0.0f, 0.0f};
#pragma unroll
        for (int kt = 0; kt < 4; ++kt) {
            half8 bf = *(const half8*)&sWT[(c * 16 + ml) * XPITCH + kt * 32 + quad * 8];
            acc = __builtin_amdgcn_mfma_f32_16x16x32_f16(a[kt], bf, acc, 0, 0, 0);
        }
        int col = c * 16 + ml;
        float bias = sB2[col];
        float w30 = sW3[col * 2], w31 = sW3[col * 2 + 1];
        float v30 = sV3[col * 2], v31 = sV3[col * 2 + 1];
#pragma unroll
        for (int r = 0; r < 4; ++r) {
            float t = fmaxf(acc[r] + bias, 0.0f);
            p0[r] += t * w30; p1[r] += t * w31;
            q0[r] += t * v30; q1[r] += t * v31;
        }
    }
#pragma unroll
    for (int mk = 1; mk <= 8; mk <<= 1) {
#pragma unroll
        for (int r = 0; r < 4; ++r) {
            p0[r] += __shfl_xor(p0[r], mk);
            p1[r] += __shfl_xor(p1[r], mk);
            q0[r] += __shfl_xor(q0[r], mk);
            q1[r] += __shfl_xor(q1[r], mk);
        }
    }
    if (ml == 0) {
        float b30 = b3[0], b31 = b3[1];
#pragma unroll
        for (int r = 0; r < 4; ++r) {
            int g = base + wv * 16 + quad * 4 + r;
            if (g < N) {
                h3[g] = make_float2(p0[r], p1[r]);
                y3[g] = make_float2(q0[r] + b30, q1[r] + b31);
            }
        }
    }
}

// ---------------- launch ----------------

extern "C" void kernel_launch(void* const* d_in, const int* in_sizes, int n_in,
                              void* d_out, int out_size, void* d_ws, size_t ws_size,
                              hipStream_t stream) {
    const float* x  = (const float*)d_in[0];
    const int*   ei = (const int*)d_in[1];
    const int*   src = ei;
    const int*   dst = ei + NE;
    const float* W1 = (const float*)d_in[2];
    const float* V1 = (const float*)d_in[3];
    const float* b1 = (const float*)d_in[4];
    const float* W2 = (const float*)d_in[5];
    const float* V2 = (const float*)d_in[6];
    const float* b2 = (const float*)d_in[7];
    const float* W3 = (const float*)d_in[8];
    const float* V3 = (const float*)d_in[9];
    const float* b3 = (const float*)d_in[10];
    float* out = (float*)d_out;

    // workspace layout (float offsets)
    float* ws = (float*)d_ws;
    int*   bcur1 = (int*)ws;                          // 49*32 (region 2048)
    int*   bcur2 = (int*)(ws + 2048);                 // 782*32 = 25024
    int*   ebase = (int*)(ws + 27136);                // NBUCK+1
    int*   rp    = (int*)(ws + 28160);                // NN+1
    float* dinv  = ws + 128512;                       // NN -> 228864
    // S region: sbdata (binA1->binA2), then perm (binB -> end)
    unsigned int* sbdata = (unsigned int*)(ws + 228864);   // 49*34816
    int*   perm  = (int*)(ws + 228864);                    // NE (aliases sbdata)
    // T region: fbdata (binA2->binB), then h3/y3 (dense23m -> agg3lsm)
    unsigned int* fbdata = (unsigned int*)(ws + 1934848);  // 782*2304
    float2* h3   = (float2*)(ws + 1934848);                // NN float2
    float2* y3   = (float2*)(ws + 1934848 + 2 * NN);       // NN float2
    // A region: aggth (agg64h -> dense23m)
    unsigned short* aggth = (unsigned short*)(ws + 8334848); // NN*64 fp16
    unsigned short* th    = (unsigned short*)(ws + 14734848);// NN*64 fp16

    const int B = 256;

    // ---- CSR build: two-level multisplit (+ dinv) ----
    hipMemsetAsync(bcur1, 0, 27072 * sizeof(int), stream);  // bcur1+bcur2 contiguous
    k_binA1<<<NBLK1, B, 0, stream>>>(src, dst, bcur1, sbdata);
    k_binA2<<<NSB * NSLICE, B, 0, stream>>>(bcur1, sbdata, bcur2, fbdata);
    k_bscan<<<1, 1024, 0, stream>>>(bcur2, ebase);
    k_binB<<<NBUCK, B, 0, stream>>>(bcur2, ebase, fbdata, rp, dinv, perm);

    // ---- layer 1 (fused gather + dense) -> fp16 th ----
    k_l1f<<<(NN * 16 + B - 1) / B, B, 0, stream>>>(rp, perm, dinv, x, W1, V1, b1, th, NN);

    // ---- layer 2: fp16 packed gather-aggregate, then MFMA dense2+3 ----
    k_agg64h<<<(NN * 64 + B - 1) / B, B, 0, stream>>>(rp, perm, dinv, th, aggth, NN);
    k_dense23m<<<(NN + 63) / 64, B, 0, stream>>>(aggth, th, W2, V2, b2, W3, V3, b3,
                                                 h3, y3, NN);

    // ---- layer 3 aggregate + log_softmax ----
    k_agg3lsm<<<(NN * 16 + B - 1) / B, B, 0, stream>>>(rp, perm, dinv,
                                                       (const float2*)h3,
                                                       (const float2*)y3, out, NN);
}

// Round 15
// 219.246 us; speedup vs baseline: 1.0257x; 1.0257x over previous
//
#include <hip/hip_runtime.h>
#include <hip/hip_fp16.h>
#include <math.h>

#define NN 100000
#define NE 1600000
#define HID 64
// fine buckets (binB granularity)
#define BN 128
#define NBUCK 782          // ceil(NN/128)
#define FBCAP 2304         // fine bucket capacity (mean 2048, +5.7 sigma)
// coarse superbuckets (binA granularity)
#define NSB 49             // ceil(NN/2048)
#define SBCAP 34816        // superbucket capacity (mean 32653, +12 sigma)
#define CHUNK1 4096
#define NBLK1 391          // ceil(NE/4096)
#define NSLICE 16          // binA2 slices per superbucket
#define SLCAP 2304         // >= ceil(SBCAP/16) = 2176
#define CSTRIDE 32         // ints between cursors (128 B)
#define XPITCH 136         // LDS row pitch in halfs (128 + 8; 272 B, 16B-aligned rows)

typedef _Float16 half8 __attribute__((ext_vector_type(8)));
typedef float floatx4 __attribute__((ext_vector_type(4)));

__device__ __forceinline__ __half2 shfl_xor_h2(__half2 v, int m) {
    unsigned int u = *(unsigned int*)&v;
    u = __shfl_xor(u, m);
    return *(__half2*)&u;
}
__device__ __forceinline__ unsigned int h2bits(__half2 v) {
    return *(unsigned int*)&v;
}
// decode packed dinv weight (15-bit fixed point, scale 1/16384)
__device__ __forceinline__ float wdec(unsigned int u) {
    return (float)(u >> 17) * 6.103515625e-05f;
}

// ---------------- CSR build: two-level multisplit ----------------

// Pass A1: multisplit edges into 49 superbuckets (dst>>11). 4096-edge chunks.
// Packed u32: src (17b) | (dst & 2047) << 17.
__global__ __launch_bounds__(256) void k_binA1(const int* __restrict__ src,
                                               const int* __restrict__ dst,
                                               int* __restrict__ bcur1,
                                               unsigned int* __restrict__ sbdata) {
    __shared__ unsigned int par[CHUNK1];
    __shared__ unsigned short rnk[CHUNK1];
    __shared__ unsigned char bkt[CHUNK1];
    __shared__ int hist[NSB];
    __shared__ int base[NSB];
    int tid = threadIdx.x;
    int e0 = blockIdx.x * CHUNK1;
    int m = NE - e0; if (m > CHUNK1) m = CHUNK1;
    if (tid < NSB) hist[tid] = 0;
    __syncthreads();
    for (int i = tid; i < m; i += 256) {
        int s = src[e0 + i], d = dst[e0 + i];
        int b = d >> 11;
        par[i] = (unsigned int)s | ((unsigned int)(d & 2047) << 17);
        bkt[i] = (unsigned char)b;
        rnk[i] = (unsigned short)atomicAdd(&hist[b], 1);
    }
    __syncthreads();
    if (tid < NSB) {
        int h = hist[tid];
        base[tid] = h ? atomicAdd(&bcur1[tid * CSTRIDE], h) : 0;
    }
    __syncthreads();
    for (int i = tid; i < m; i += 256) {
        int b = bkt[i];
        int pos = base[b] + rnk[i];
        if (pos < SBCAP) sbdata[(size_t)b * SBCAP + pos] = par[i];
    }
}

// Pass A2: split each superbucket into its 16 fine buckets (16 slices each).
// Output u32: src (17b) | dlocal(7b) << 17.
__global__ __launch_bounds__(256) void k_binA2(const int* __restrict__ bcur1,
                                               const unsigned int* __restrict__ sbdata,
                                               int* __restrict__ bcur2,
                                               unsigned int* __restrict__ fbdata) {
    __shared__ unsigned int par[SLCAP];
    __shared__ unsigned short rnk[SLCAP];
    __shared__ unsigned char bkt[SLCAP];
    __shared__ int hist[16];
    __shared__ int base[16];
    int tid = threadIdx.x;
    int sb = blockIdx.x >> 4, sl = blockIdx.x & 15;
    int m = bcur1[sb * CSTRIDE]; if (m > SBCAP) m = SBCAP;
    int L = (m + NSLICE - 1) >> 4;
    int lo = sl * L;
    int cnt = m - lo; if (cnt > L) cnt = L; if (cnt < 0) cnt = 0;
    if (tid < 16) hist[tid] = 0;
    __syncthreads();
    const unsigned int* sp = sbdata + (size_t)sb * SBCAP + lo;
    for (int i = tid; i < cnt; i += 256) {
        unsigned int u = sp[i];
        int dlow = (u >> 17) & 2047;
        int f = dlow >> 7;
        par[i] = (u & 0x1ffffu) | ((unsigned int)(dlow & 127) << 17);
        bkt[i] = (unsigned char)f;
        rnk[i] = (unsigned short)atomicAdd(&hist[f], 1);
    }
    __syncthreads();
    if (tid < 16) {
        int h = hist[tid];
        base[tid] = h ? atomicAdd(&bcur2[(sb * 16 + tid) * CSTRIDE], h) : 0;
    }
    __syncthreads();
    for (int i = tid; i < cnt; i += 256) {
        int f = bkt[i];
        int pos = base[f] + rnk[i];
        if (pos < FBCAP) fbdata[(size_t)(sb * 16 + f) * FBCAP + pos] = par[i];
    }
}

// exclusive scan of fine-bucket totals — wave-level scan (2 barriers).
__global__ void k_bscan(const int* __restrict__ bcur2, int* __restrict__ ebase) {
    __shared__ int ls[16];
    int t = threadIdx.x;
    int lane = t & 63, wid = t >> 6;
    int v = 0;
    if (t < NBUCK) {
        int m = bcur2[t * CSTRIDE];
        v = (m < FBCAP) ? m : FBCAP;
    }
    int orig = v;
    for (int off = 1; off < 64; off <<= 1) {
        int u = __shfl_up(v, off);
        if (lane >= off) v += u;
    }
    if (lane == 63) ls[wid] = v;
    __syncthreads();
    if (wid == 0) {
        int w = (lane < 16) ? ls[lane] : 0;
        for (int off = 1; off < 16; off <<= 1) {
            int u = __shfl_up(w, off);
            if (lane >= off) w += u;
        }
        if (lane < 16) ls[lane] = w;
    }
    __syncthreads();
    int base = wid ? ls[wid - 1] : 0;
    int incl = base + v;
    if (t < NBUCK) ebase[t] = incl - orig;
    if (t == NBUCK - 1) ebase[NBUCK] = incl;  // = NE
}

// Pass B: per fine bucket (256 threads) — stage edges in LDS, count per node,
// dinv, rp, then scatter perm (src only) within the bucket's contiguous span.
__global__ __launch_bounds__(256) void k_binB(const int* __restrict__ bcur2,
                                              const int* __restrict__ ebase,
                                              const unsigned int* __restrict__ fbdata,
                                              int* __restrict__ rp, float* __restrict__ dinv,
                                              int* __restrict__ perm) {
    __shared__ unsigned int se[FBCAP];
    __shared__ int cnt[BN];
    __shared__ int scn[BN];
    int b = blockIdx.x, tid = threadIdx.x;
    int m = bcur2[b * CSTRIDE]; if (m > FBCAP) m = FBCAP;
    int base = ebase[b];
    for (int i = tid; i < m; i += 256) se[i] = fbdata[(size_t)b * FBCAP + i];
    if (tid < BN) cnt[tid] = 0;
    __syncthreads();
    for (int i = tid; i < m; i += 256) atomicAdd(&cnt[se[i] >> 17], 1);
    __syncthreads();
    int c = (tid < BN) ? cnt[tid] : 0;
    int g = b * BN + tid;
    if (tid < BN && g < NN) dinv[g] = (c > 0) ? rsqrtf((float)c) : 0.0f;
    if (tid < BN) scn[tid] = c;
    __syncthreads();
    for (int off = 1; off < BN; off <<= 1) {
        int u = (tid >= off && tid < BN) ? scn[tid - off] : 0;
        __syncthreads();
        if (tid < BN) scn[tid] += u;
        __syncthreads();
    }
    if (tid < BN) {
        int excl = scn[tid] - c;
        if (g < NN) rp[g] = base + excl;
        cnt[tid] = excl;  // reuse as running cursor
    }
    if (b == NBUCK - 1 && tid == 0) rp[NN] = ebase[NBUCK];
    __syncthreads();
    for (int i = tid; i < m; i += 256) {
        unsigned int u = se[i];
        int pos = atomicAdd(&cnt[u >> 17], 1);
        perm[base + pos] = (int)(u & 0x1ffffu);
    }
}

// pack dinv[src] (15-bit fixed point) into the free high bits of perm.
// Pays the 1.6M random dinv gathers ONCE instead of in 3 aggregation kernels.
__global__ __launch_bounds__(256) void k_wpack(int* __restrict__ perm,
                                               const float* __restrict__ dinv, int E) {
    int i = blockIdx.x * blockDim.x + threadIdx.x;
    if (i < E) {
        unsigned int s = (unsigned int)perm[i];
        int q = __float2int_rn(dinv[s] * 16384.0f);
        perm[i] = (int)(s | ((unsigned int)q << 17));
    }
}

// ---------------- layer 1 fused: aggregate x + dense1 -> fp16 th ----------------

__global__ __launch_bounds__(256) void k_l1f(
        const int* __restrict__ rp, const unsigned int* __restrict__ pw,
        const float* __restrict__ dinv, const float* __restrict__ x,
        const float* __restrict__ W, const float* __restrict__ V,
        const float* __restrict__ b, unsigned short* __restrict__ th, int N) {
    __shared__ float sW[640], sV[640];
    for (int i = threadIdx.x; i < 640; i += 256) { sW[i] = W[i]; sV[i] = V[i]; }
    __syncthreads();
    int n = (blockIdx.x * 256 + threadIdx.x) >> 4;
    if (n >= N) return;
    int sub = threadIdx.x & 15;
    int beg = rp[n], end = rp[n + 1];
    float ag[10];
#pragma unroll
    for (int k = 0; k < 10; ++k) ag[k] = 0.0f;
    for (int j = beg + sub; j < end; j += 16) {
        unsigned int pe = pw[j];
        int s = pe & 0x1ffff;
        float w = wdec(pe);
        const float2* xr = (const float2*)(x + (size_t)s * 10);
        float2 v0 = xr[0], v1 = xr[1], v2 = xr[2], v3 = xr[3], v4 = xr[4];
        ag[0] += w * v0.x; ag[1] += w * v0.y; ag[2] += w * v1.x; ag[3] += w * v1.y;
        ag[4] += w * v2.x; ag[5] += w * v2.y; ag[6] += w * v3.x; ag[7] += w * v3.y;
        ag[8] += w * v4.x; ag[9] += w * v4.y;
    }
#pragma unroll
    for (int mk = 1; mk <= 8; mk <<= 1) {
#pragma unroll
        for (int k = 0; k < 10; ++k) ag[k] += __shfl_xor(ag[k], mk);
    }
    float dn = dinv[n];
#pragma unroll
    for (int k = 0; k < 10; ++k) ag[k] *= dn;
    const float2* xn = (const float2*)(x + (size_t)n * 10);
    float2 x0 = xn[0], x1 = xn[1], x2 = xn[2], x3 = xn[3], x4 = xn[4];
    float xv[10] = {x0.x, x0.y, x1.x, x1.y, x2.x, x2.y, x3.x, x3.y, x4.x, x4.y};
    int f0 = sub * 4;
    float4 bb = *(const float4*)(b + f0);
    float acc[4] = {bb.x, bb.y, bb.z, bb.w};
#pragma unroll
    for (int k = 0; k < 10; ++k) {
        float4 wq = *(const float4*)&sW[k * HID + f0];
        float4 vq = *(const float4*)&sV[k * HID + f0];
        acc[0] += ag[k] * wq.x + xv[k] * vq.x;
        acc[1] += ag[k] * wq.y + xv[k] * vq.y;
        acc[2] += ag[k] * wq.z + xv[k] * vq.z;
        acc[3] += ag[k] * wq.w + xv[k] * vq.w;
    }
    __half2 lo = __floats2half2_rn(fmaxf(acc[0], 0.0f), fmaxf(acc[1], 0.0f));
    __half2 hi = __floats2half2_rn(fmaxf(acc[2], 0.0f), fmaxf(acc[3], 0.0f));
    *(uint2*)(th + (size_t)n * HID + f0) = make_uint2(h2bits(lo), h2bits(hi));
}

// ---------------- layer-2 aggregation (gather, fp16 packed math) ----------------

// Wave per node: 8 edge-groups x 8 lanes, 2 edges unrolled per group
// -> 16 independent 128 B lines in flight per wave.
__global__ __launch_bounds__(256) void k_agg64h(
        const int* __restrict__ rp, const unsigned int* __restrict__ pw,
        const float* __restrict__ dinv, const unsigned short* __restrict__ th,
        unsigned short* __restrict__ aggth, int N) {
    int wid = (blockIdx.x * blockDim.x + threadIdx.x) >> 6;
    if (wid >= N) return;
    int n = __builtin_amdgcn_readfirstlane(wid);
    int lane = threadIdx.x & 63;
    int grp = lane >> 3;
    int sub = lane & 7;
    int beg = rp[n], end = rp[n + 1];
    __half2 a0 = __float2half2_rn(0.0f), a1 = a0, a2 = a0, a3 = a0;
    int j = beg + grp;
    for (; j + 8 < end; j += 16) {
        unsigned int pa = pw[j], pb = pw[j + 8];
        int sa = pa & 0x1ffff, sb = pb & 0x1ffff;
        __half2 wa = __float2half2_rn(wdec(pa));
        __half2 wb = __float2half2_rn(wdec(pb));
        uint4 ua = *(const uint4*)(th + (size_t)sa * HID + sub * 8);
        uint4 ub = *(const uint4*)(th + (size_t)sb * HID + sub * 8);
        a0 = __hfma2(wa, *(__half2*)&ua.x, a0);
        a1 = __hfma2(wa, *(__half2*)&ua.y, a1);
        a2 = __hfma2(wa, *(__half2*)&ua.z, a2);
        a3 = __hfma2(wa, *(__half2*)&ua.w, a3);
        a0 = __hfma2(wb, *(__half2*)&ub.x, a0);
        a1 = __hfma2(wb, *(__half2*)&ub.y, a1);
        a2 = __hfma2(wb, *(__half2*)&ub.z, a2);
        a3 = __hfma2(wb, *(__half2*)&ub.w, a3);
    }
    if (j < end) {
        unsigned int pa = pw[j];
        int sa = pa & 0x1ffff;
        __half2 wa = __float2half2_rn(wdec(pa));
        uint4 ua = *(const uint4*)(th + (size_t)sa * HID + sub * 8);
        a0 = __hfma2(wa, *(__half2*)&ua.x, a0);
        a1 = __hfma2(wa, *(__half2*)&ua.y, a1);
        a2 = __hfma2(wa, *(__half2*)&ua.z, a2);
        a3 = __hfma2(wa, *(__half2*)&ua.w, a3);
    }
#pragma unroll
    for (int m = 8; m < 64; m <<= 1) {
        a0 = __hadd2(a0, shfl_xor_h2(a0, m));
        a1 = __hadd2(a1, shfl_xor_h2(a1, m));
        a2 = __hadd2(a2, shfl_xor_h2(a2, m));
        a3 = __hadd2(a3, shfl_xor_h2(a3, m));
    }
    if (grp == 0) {
        __half2 dn2 = __float2half2_rn(dinv[n]);
        uint4 o;
        o.x = h2bits(__hmul2(dn2, a0));
        o.y = h2bits(__hmul2(dn2, a1));
        o.z = h2bits(__hmul2(dn2, a2));
        o.w = h2bits(__hmul2(dn2, a3));
        *(uint4*)(aggth + (size_t)n * HID + sub * 8) = o;
    }
}

// layer-3 aggregation + log_softmax: 16 lanes per node, lane-per-edge.
__global__ __launch_bounds__(256) void k_agg3lsm(const int* __restrict__ rp,
                                                 const unsigned int* __restrict__ pw,
                                                 const float* __restrict__ dinv,
                                                 const float2* __restrict__ h3,
                                                 const float2* __restrict__ y3,
                                                 float* __restrict__ out, int N) {
    int n = (blockIdx.x * 256 + threadIdx.x) >> 4;
    if (n >= N) return;
    int sl = threadIdx.x & 15;
    int beg = rp[n], end = rp[n + 1];
    float a0 = 0.0f, a1 = 0.0f;
    for (int j = beg + sl; j < end; j += 16) {
        unsigned int pe = pw[j];
        int s = pe & 0x1ffff;
        float w = wdec(pe);
        float2 hh = h3[s];
        a0 += w * hh.x;
        a1 += w * hh.y;
    }
#pragma unroll
    for (int mk = 1; mk <= 8; mk <<= 1) {
        a0 += __shfl_xor(a0, mk);
        a1 += __shfl_xor(a1, mk);
    }
    if (sl == 0) {
        float dn = dinv[n];
        float2 yy = y3[n];
        float z0 = dn * a0 + yy.x;
        float z1 = dn * a1 + yy.y;
        float m = fmaxf(z0, z1);
        float l = m + logf(expf(z0 - m) + expf(z1 - m));
        out[n * 2 + 0] = z0 - l;
        out[n * 2 + 1] = z1 - l;
    }
}

// ---------------- fused dense 2+3 via MFMA ----------------

__global__ __launch_bounds__(256) void k_dense23m(
        const unsigned short* __restrict__ aggth, const unsigned short* __restrict__ th,
        const float* __restrict__ W, const float* __restrict__ V,
        const float* __restrict__ b, const float* __restrict__ W3,
        const float* __restrict__ V3, const float* __restrict__ b3,
        float2* __restrict__ h3, float2* __restrict__ y3, int N) {
    __shared__ _Float16 sX[64 * XPITCH];    // [node][K]  K: 0..63 aggth, 64..127 th
    __shared__ _Float16 sWT[64 * XPITCH];   // [feat][K]  K: 0..63 W2,   64..127 V2
    __shared__ float sB2[64];
    __shared__ float sW3[128], sV3[128];
    int tid = threadIdx.x;
    int base = blockIdx.x * 64;
    {
        int f = tid & 63;
        int g = tid >> 6;                      // 0..3
        const float* Wsrc = (g < 2) ? W : V;
        int kbase = (g & 1) * 32;
        int Kbase = (g < 2) ? kbase : (64 + kbase);
#pragma unroll
        for (int k2 = 0; k2 < 32; k2 += 2) {
            float w0 = Wsrc[(kbase + k2) * 64 + f];
            float w1 = Wsrc[(kbase + k2 + 1) * 64 + f];
            __half2 h = __floats2half2_rn(w0, w1);
            *(unsigned int*)&sWT[f * XPITCH + Kbase + k2] = h2bits(h);
        }
        if (tid < 64) sB2[tid] = b[tid];
        if (tid < 128) { sW3[tid] = W3[tid]; sV3[tid] = V3[tid]; }
    }
    {
        int n = tid >> 2, p = tid & 3;
        int g = base + n;
        uint4 z = make_uint4(0, 0, 0, 0);
        uint4 a0 = z, a1 = z, c0 = z, c1 = z;
        if (g < N) {
            const uint4* ap = (const uint4*)(aggth + (size_t)g * HID + p * 16);
            const uint4* cp = (const uint4*)(th + (size_t)g * HID + p * 16);
            a0 = ap[0]; a1 = ap[1];
            c0 = cp[0]; c1 = cp[1];
        }
        *(uint4*)&sX[n * XPITCH + p * 16] = a0;
        *(uint4*)&sX[n * XPITCH + p * 16 + 8] = a1;
        *(uint4*)&sX[n * XPITCH + 64 + p * 16] = c0;
        *(uint4*)&sX[n * XPITCH + 64 + p * 16 + 8] = c1;
    }
    __syncthreads();
    int lane = tid & 63;
    int wv = tid >> 6;          // wave id: rows wv*16 .. wv*16+15
    int ml = lane & 15, quad = lane >> 4;
    half8 a[4];
#pragma unroll
    for (int kt = 0; kt < 4; ++kt)
        a[kt] = *(const half8*)&sX[(wv * 16 + ml) * XPITCH + kt * 32 + quad * 8];
    float p0[4] = {}, p1[4] = {}, q0[4] = {}, q1[4] = {};
#pragma unroll
    for (int c = 0; c < 4; ++c) {
        floatx4 acc = {0.0f, 0.0f, 0.0f, 0.0f};
#pragma unroll
        for (int kt = 0; kt < 4; ++kt) {
            half8 bf = *(const half8*)&sWT[(c * 16 + ml) * XPITCH + kt * 32 + quad * 8];
            acc = __builtin_amdgcn_mfma_f32_16x16x32_f16(a[kt], bf, acc, 0, 0, 0);
        }
        int col = c * 16 + ml;
        float bias = sB2[col];
        float w30 = sW3[col * 2], w31 = sW3[col * 2 + 1];
        float v30 = sV3[col * 2], v31 = sV3[col * 2 + 1];
#pragma unroll
        for (int r = 0; r < 4; ++r) {
            float t = fmaxf(acc[r] + bias, 0.0f);
            p0[r] += t * w30; p1[r] += t * w31;
            q0[r] += t * v30; q1[r] += t * v31;
        }
    }
#pragma unroll
    for (int mk = 1; mk <= 8; mk <<= 1) {
#pragma unroll
        for (int r = 0; r < 4; ++r) {
            p0[r] += __shfl_xor(p0[r], mk);
            p1[r] += __shfl_xor(p1[r], mk);
            q0[r] += __shfl_xor(q0[r], mk);
            q1[r] += __shfl_xor(q1[r], mk);
        }
    }
    if (ml == 0) {
        float b30 = b3[0], b31 = b3[1];
#pragma unroll
        for (int r = 0; r < 4; ++r) {
            int g = base + wv * 16 + quad * 4 + r;
            if (g < N) {
                h3[g] = make_float2(p0[r], p1[r]);
                y3[g] = make_float2(q0[r] + b30, q1[r] + b31);
            }
        }
    }
}

// ---------------- launch ----------------

extern "C" void kernel_launch(void* const* d_in, const int* in_sizes, int n_in,
                              void* d_out, int out_size, void* d_ws, size_t ws_size,
                              hipStream_t stream) {
    const float* x  = (const float*)d_in[0];
    const int*   ei = (const int*)d_in[1];
    const int*   src = ei;
    const int*   dst = ei + NE;
    const float* W1 = (const float*)d_in[2];
    const float* V1 = (const float*)d_in[3];
    const float* b1 = (const float*)d_in[4];
    const float* W2 = (const float*)d_in[5];
    const float* V2 = (const float*)d_in[6];
    const float* b2 = (const float*)d_in[7];
    const float* W3 = (const float*)d_in[8];
    const float* V3 = (const float*)d_in[9];
    const float* b3 = (const float*)d_in[10];
    float* out = (float*)d_out;

    // workspace layout (float offsets)
    float* ws = (float*)d_ws;
    int*   bcur1 = (int*)ws;                          // 49*32 (region 2048)
    int*   bcur2 = (int*)(ws + 2048);                 // 782*32 = 25024
    int*   ebase = (int*)(ws + 27136);                // NBUCK+1
    int*   rp    = (int*)(ws + 28160);                // NN+1
    float* dinv  = ws + 128512;                       // NN -> 228864
    // S region: sbdata (binA1->binA2), then perm (binB -> end)
    unsigned int* sbdata = (unsigned int*)(ws + 228864);   // 49*34816
    int*   perm  = (int*)(ws + 228864);                    // NE (aliases sbdata)
    // T region: fbdata (binA2->binB), then h3/y3 (dense23m -> agg3lsm)
    unsigned int* fbdata = (unsigned int*)(ws + 1934848);  // 782*2304
    float2* h3   = (float2*)(ws + 1934848);                // NN float2
    float2* y3   = (float2*)(ws + 1934848 + 2 * NN);       // NN float2
    // A region: aggth (agg64h -> dense23m)
    unsigned short* aggth = (unsigned short*)(ws + 8334848); // NN*64 fp16
    unsigned short* th    = (unsigned short*)(ws + 14734848);// NN*64 fp16

    const int B = 256;

    // ---- CSR build: two-level multisplit (+ dinv) ----
    hipMemsetAsync(bcur1, 0, 27072 * sizeof(int), stream);  // bcur1+bcur2 contiguous
    k_binA1<<<NBLK1, B, 0, stream>>>(src, dst, bcur1, sbdata);
    k_binA2<<<NSB * NSLICE, B, 0, stream>>>(bcur1, sbdata, bcur2, fbdata);
    k_bscan<<<1, 1024, 0, stream>>>(bcur2, ebase);
    k_binB<<<NBUCK, B, 0, stream>>>(bcur2, ebase, fbdata, rp, dinv, perm);
    k_wpack<<<(NE + B - 1) / B, B, 0, stream>>>(perm, dinv, NE);

    // ---- layer 1 (fused gather + dense) -> fp16 th ----
    k_l1f<<<(NN * 16 + B - 1) / B, B, 0, stream>>>(rp, (const unsigned int*)perm,
                                                   dinv, x, W1, V1, b1, th, NN);

    // ---- layer 2: fp16 packed gather-aggregate, then MFMA dense2+3 ----
    k_agg64h<<<(NN * 64 + B - 1) / B, B, 0, stream>>>(rp, (const unsigned int*)perm,
                                                      dinv, th, aggth, NN);
    k_dense23m<<<(NN + 63) / 64, B, 0, stream>>>(aggth, th, W2, V2, b2, W3, V3, b3,
                                                 h3, y3, NN);

    // ---- layer 3 aggregate + log_softmax ----
    k_agg3lsm<<<(NN * 16 + B - 1) / B, B, 0, stream>>>(rp, (const unsigned int*)perm,
                                                       dinv, (const float2*)h3,
                                                       (const float2*)y3, out, NN);
}

// Round 17
// 212.315 us; speedup vs baseline: 1.0592x; 1.0326x over previous
//
#include <hip/hip_runtime.h>
#include <hip/hip_fp16.h>
#include <math.h>

#define NN 100000
#define NE 1600000
#define HID 64
// fine buckets (binB granularity)
#define BN 128
#define NBUCK 782          // ceil(NN/128)
#define FBCAP 2304         // fine bucket capacity (mean 2048, +5.7 sigma)
// coarse superbuckets (binA granularity)
#define NSB 49             // ceil(NN/2048)
#define SBCAP 34816        // superbucket capacity (mean 32653, +12 sigma)
#define CHUNK1 4096
#define NBLK1 391          // ceil(NE/4096)
#define NSLICE 16          // binA2 slices per superbucket
#define SLCAP 2304         // >= ceil(SBCAP/16) = 2176
#define CSTRIDE 32         // ints between cursors (128 B)
#define XPITCH 136         // LDS row pitch in halfs (128 + 8; 272 B, 16B-aligned rows)

typedef _Float16 half8 __attribute__((ext_vector_type(8)));
typedef float floatx4 __attribute__((ext_vector_type(4)));

__device__ __forceinline__ __half2 shfl_xor_h2(__half2 v, int m) {
    unsigned int u = *(unsigned int*)&v;
    u = __shfl_xor(u, m);
    return *(__half2*)&u;
}
__device__ __forceinline__ unsigned int h2bits(__half2 v) {
    return *(unsigned int*)&v;
}

// ---------------- CSR build: two-level multisplit ----------------

// Pass A1: multisplit edges into 49 superbuckets (dst>>11). 4096-edge chunks.
// Packed u32: src (17b) | (dst & 2047) << 17.
__global__ __launch_bounds__(256) void k_binA1(const int* __restrict__ src,
                                               const int* __restrict__ dst,
                                               int* __restrict__ bcur1,
                                               unsigned int* __restrict__ sbdata) {
    __shared__ unsigned int par[CHUNK1];
    __shared__ unsigned short rnk[CHUNK1];
    __shared__ unsigned char bkt[CHUNK1];
    __shared__ int hist[NSB];
    __shared__ int base[NSB];
    int tid = threadIdx.x;
    int e0 = blockIdx.x * CHUNK1;
    int m = NE - e0; if (m > CHUNK1) m = CHUNK1;
    if (tid < NSB) hist[tid] = 0;
    __syncthreads();
    for (int i = tid; i < m; i += 256) {
        int s = src[e0 + i], d = dst[e0 + i];
        int b = d >> 11;
        par[i] = (unsigned int)s | ((unsigned int)(d & 2047) << 17);
        bkt[i] = (unsigned char)b;
        rnk[i] = (unsigned short)atomicAdd(&hist[b], 1);
    }
    __syncthreads();
    if (tid < NSB) {
        int h = hist[tid];
        base[tid] = h ? atomicAdd(&bcur1[tid * CSTRIDE], h) : 0;
    }
    __syncthreads();
    for (int i = tid; i < m; i += 256) {
        int b = bkt[i];
        int pos = base[b] + rnk[i];
        if (pos < SBCAP) sbdata[(size_t)b * SBCAP + pos] = par[i];
    }
}

// Pass A2: split each superbucket into its 16 fine buckets (16 slices each).
// Output u32: src (17b) | dlocal(7b) << 17.
__global__ __launch_bounds__(256) void k_binA2(const int* __restrict__ bcur1,
                                               const unsigned int* __restrict__ sbdata,
                                               int* __restrict__ bcur2,
                                               unsigned int* __restrict__ fbdata) {
    __shared__ unsigned int par[SLCAP];
    __shared__ unsigned short rnk[SLCAP];
    __shared__ unsigned char bkt[SLCAP];
    __shared__ int hist[16];
    __shared__ int base[16];
    int tid = threadIdx.x;
    int sb = blockIdx.x >> 4, sl = blockIdx.x & 15;
    int m = bcur1[sb * CSTRIDE]; if (m > SBCAP) m = SBCAP;
    int L = (m + NSLICE - 1) >> 4;
    int lo = sl * L;
    int cnt = m - lo; if (cnt > L) cnt = L; if (cnt < 0) cnt = 0;
    if (tid < 16) hist[tid] = 0;
    __syncthreads();
    const unsigned int* sp = sbdata + (size_t)sb * SBCAP + lo;
    for (int i = tid; i < cnt; i += 256) {
        unsigned int u = sp[i];
        int dlow = (u >> 17) & 2047;
        int f = dlow >> 7;
        par[i] = (u & 0x1ffffu) | ((unsigned int)(dlow & 127) << 17);
        bkt[i] = (unsigned char)f;
        rnk[i] = (unsigned short)atomicAdd(&hist[f], 1);
    }
    __syncthreads();
    if (tid < 16) {
        int h = hist[tid];
        base[tid] = h ? atomicAdd(&bcur2[(sb * 16 + tid) * CSTRIDE], h) : 0;
    }
    __syncthreads();
    for (int i = tid; i < cnt; i += 256) {
        int f = bkt[i];
        int pos = base[f] + rnk[i];
        if (pos < FBCAP) fbdata[(size_t)(sb * 16 + f) * FBCAP + pos] = par[i];
    }
}

// exclusive scan of fine-bucket totals — wave-level scan (2 barriers).
__global__ void k_bscan(const int* __restrict__ bcur2, int* __restrict__ ebase) {
    __shared__ int ls[16];
    int t = threadIdx.x;
    int lane = t & 63, wid = t >> 6;
    int v = 0;
    if (t < NBUCK) {
        int m = bcur2[t * CSTRIDE];
        v = (m < FBCAP) ? m : FBCAP;
    }
    int orig = v;
    for (int off = 1; off < 64; off <<= 1) {
        int u = __shfl_up(v, off);
        if (lane >= off) v += u;
    }
    if (lane == 63) ls[wid] = v;
    __syncthreads();
    if (wid == 0) {
        int w = (lane < 16) ? ls[lane] : 0;
        for (int off = 1; off < 16; off <<= 1) {
            int u = __shfl_up(w, off);
            if (lane >= off) w += u;
        }
        if (lane < 16) ls[lane] = w;
    }
    __syncthreads();
    int base = wid ? ls[wid - 1] : 0;
    int incl = base + v;
    if (t < NBUCK) ebase[t] = incl - orig;
    if (t == NBUCK - 1) ebase[NBUCK] = incl;  // = NE
}

// Pass B: per fine bucket (256 threads) — single-pass stage+rank, shfl scan,
// atomic-free scatter of perm, dinv, and y = dinv * x rows for owned nodes.
__global__ __launch_bounds__(256) void k_binB(const int* __restrict__ bcur2,
                                              const int* __restrict__ ebase,
                                              const unsigned int* __restrict__ fbdata,
                                              int* __restrict__ rp, float* __restrict__ dinv,
                                              int* __restrict__ perm,
                                              const float* __restrict__ x,
                                              float* __restrict__ y) {
    __shared__ unsigned int se[FBCAP];      // 9.2 KB
    __shared__ unsigned short rnk[FBCAP];   // 4.6 KB
    __shared__ int cnt[BN];
    __shared__ int ex[BN];
    __shared__ float sdv[BN];
    __shared__ int wsum[2];
    int b = blockIdx.x, tid = threadIdx.x;
    int m = bcur2[b * CSTRIDE]; if (m > FBCAP) m = FBCAP;
    int base = ebase[b];
    if (tid < BN) cnt[tid] = 0;
    __syncthreads();
    // stage + rank in one pass
    for (int i = tid; i < m; i += 256) {
        unsigned int u = fbdata[(size_t)b * FBCAP + i];
        se[i] = u;
        rnk[i] = (unsigned short)atomicAdd(&cnt[u >> 17], 1);
    }
    __syncthreads();
    // shfl scan over 128 counts (waves 0,1)
    if (tid < BN) {
        int c = cnt[tid];
        int v = c;
        int lane = tid & 63;
        for (int off = 1; off < 64; off <<= 1) {
            int u = __shfl_up(v, off);
            if (lane >= off) v += u;
        }
        if (lane == 63) wsum[tid >> 6] = v;
        int g = b * BN + tid;
        float dv = (c > 0) ? rsqrtf((float)c) : 0.0f;
        sdv[tid] = dv;
        if (g < NN) dinv[g] = dv;
        cnt[tid] = v - c;   // exclusive within wave
    }
    __syncthreads();
    if (tid < BN) {
        int excl = cnt[tid] + ((tid >= 64) ? wsum[0] : 0);
        ex[tid] = excl;
        int g = b * BN + tid;
        if (g < NN) rp[g] = base + excl;
    }
    if (b == NBUCK - 1 && tid == 0) rp[NN] = ebase[NBUCK];
    __syncthreads();
    // atomic-free scatter
    for (int i = tid; i < m; i += 256) {
        unsigned int u = se[i];
        int dl = u >> 17;
        perm[base + ex[dl] + rnk[i]] = (int)(u & 0x1ffffu);
    }
    // y = dinv * x for owned nodes (coalesced)
    {
        int nbase = b * BN;
        int lim = NN - nbase; if (lim > BN) lim = BN;
        int tot = lim * 10;
        for (int idx = tid; idx < tot; idx += 256) {
            int nl = idx / 10;
            int k = idx - nl * 10;
            y[(size_t)(nbase + nl) * 10 + k] = sdv[nl] * x[(size_t)(nbase + nl) * 10 + k];
        }
    }
}

// ---------------- layer 1 fused: aggregate y + dense1 -> fp16 th, th2 ----------------

// 16 lanes per node. agg = dinv[n] * sum_s y[s] (y pre-scaled by dinv[s]).
// Emits th = fp16(t) (V-path) and th2 = fp16(dinv[n]*t) (gather source).
__global__ __launch_bounds__(256) void k_l1f(
        const int* __restrict__ rp, const int* __restrict__ perm,
        const float* __restrict__ dinv, const float* __restrict__ x,
        const float* __restrict__ y,
        const float* __restrict__ W, const float* __restrict__ V,
        const float* __restrict__ b, unsigned short* __restrict__ th,
        unsigned short* __restrict__ th2, int N) {
    __shared__ float sW[640], sV[640];
    for (int i = threadIdx.x; i < 640; i += 256) { sW[i] = W[i]; sV[i] = V[i]; }
    __syncthreads();
    int n = (blockIdx.x * 256 + threadIdx.x) >> 4;
    if (n >= N) return;
    int sub = threadIdx.x & 15;
    int beg = rp[n], end = rp[n + 1];
    float ag[10];
#pragma unroll
    for (int k = 0; k < 10; ++k) ag[k] = 0.0f;
    for (int j = beg + sub; j < end; j += 16) {
        int s = perm[j];
        const float2* yr = (const float2*)(y + (size_t)s * 10);
        float2 v0 = yr[0], v1 = yr[1], v2 = yr[2], v3 = yr[3], v4 = yr[4];
        ag[0] += v0.x; ag[1] += v0.y; ag[2] += v1.x; ag[3] += v1.y;
        ag[4] += v2.x; ag[5] += v2.y; ag[6] += v3.x; ag[7] += v3.y;
        ag[8] += v4.x; ag[9] += v4.y;
    }
#pragma unroll
    for (int mk = 1; mk <= 8; mk <<= 1) {
#pragma unroll
        for (int k = 0; k < 10; ++k) ag[k] += __shfl_xor(ag[k], mk);
    }
    float dn = dinv[n];
#pragma unroll
    for (int k = 0; k < 10; ++k) ag[k] *= dn;
    const float2* xn = (const float2*)(x + (size_t)n * 10);
    float2 x0 = xn[0], x1 = xn[1], x2 = xn[2], x3 = xn[3], x4 = xn[4];
    float xv[10] = {x0.x, x0.y, x1.x, x1.y, x2.x, x2.y, x3.x, x3.y, x4.x, x4.y};
    int f0 = sub * 4;
    float4 bb = *(const float4*)(b + f0);
    float acc[4] = {bb.x, bb.y, bb.z, bb.w};
#pragma unroll
    for (int k = 0; k < 10; ++k) {
        float4 wq = *(const float4*)&sW[k * HID + f0];
        float4 vq = *(const float4*)&sV[k * HID + f0];
        acc[0] += ag[k] * wq.x + xv[k] * vq.x;
        acc[1] += ag[k] * wq.y + xv[k] * vq.y;
        acc[2] += ag[k] * wq.z + xv[k] * vq.z;
        acc[3] += ag[k] * wq.w + xv[k] * vq.w;
    }
    float t0 = fmaxf(acc[0], 0.0f), t1 = fmaxf(acc[1], 0.0f);
    float t2 = fmaxf(acc[2], 0.0f), t3 = fmaxf(acc[3], 0.0f);
    __half2 lo = __floats2half2_rn(t0, t1);
    __half2 hi = __floats2half2_rn(t2, t3);
    *(uint2*)(th + (size_t)n * HID + f0) = make_uint2(h2bits(lo), h2bits(hi));
    __half2 lo2 = __floats2half2_rn(dn * t0, dn * t1);
    __half2 hi2 = __floats2half2_rn(dn * t2, dn * t3);
    *(uint2*)(th2 + (size_t)n * HID + f0) = make_uint2(h2bits(lo2), h2bits(hi2));
}

// ---------------- layer-2 aggregation: pure row sum of th2 ----------------

// aggth[n] = fp16(dinv[n] * sum_s th2[s]). Wave per node: 8 groups x 8 lanes,
// 2 edges unrolled -> 16 independent 128 B lines in flight per wave.
__global__ __launch_bounds__(256) void k_agg64h(
        const int* __restrict__ rp, const int* __restrict__ perm,
        const float* __restrict__ dinv, const unsigned short* __restrict__ th2,
        unsigned short* __restrict__ aggth, int N) {
    int wid = (blockIdx.x * blockDim.x + threadIdx.x) >> 6;
    if (wid >= N) return;
    int n = __builtin_amdgcn_readfirstlane(wid);
    int lane = threadIdx.x & 63;
    int grp = lane >> 3;
    int sub = lane & 7;
    int beg = rp[n], end = rp[n + 1];
    __half2 a0 = __float2half2_rn(0.0f), a1 = a0, a2 = a0, a3 = a0;
    int j = beg + grp;
    for (; j + 8 < end; j += 16) {
        int sa = perm[j], sb = perm[j + 8];
        uint4 ua = *(const uint4*)(th2 + (size_t)sa * HID + sub * 8);
        uint4 ub = *(const uint4*)(th2 + (size_t)sb * HID + sub * 8);
        a0 = __hadd2(a0, __hadd2(*(__half2*)&ua.x, *(__half2*)&ub.x));
        a1 = __hadd2(a1, __hadd2(*(__half2*)&ua.y, *(__half2*)&ub.y));
        a2 = __hadd2(a2, __hadd2(*(__half2*)&ua.z, *(__half2*)&ub.z));
        a3 = __hadd2(a3, __hadd2(*(__half2*)&ua.w, *(__half2*)&ub.w));
    }
    if (j < end) {
        int sa = perm[j];
        uint4 ua = *(const uint4*)(th2 + (size_t)sa * HID + sub * 8);
        a0 = __hadd2(a0, *(__half2*)&ua.x);
        a1 = __hadd2(a1, *(__half2*)&ua.y);
        a2 = __hadd2(a2, *(__half2*)&ua.z);
        a3 = __hadd2(a3, *(__half2*)&ua.w);
    }
#pragma unroll
    for (int m = 8; m < 64; m <<= 1) {
        a0 = __hadd2(a0, shfl_xor_h2(a0, m));
        a1 = __hadd2(a1, shfl_xor_h2(a1, m));
        a2 = __hadd2(a2, shfl_xor_h2(a2, m));
        a3 = __hadd2(a3, shfl_xor_h2(a3, m));
    }
    if (grp == 0) {
        __half2 dn2 = __float2half2_rn(dinv[n]);
        uint4 o;
        o.x = h2bits(__hmul2(dn2, a0));
        o.y = h2bits(__hmul2(dn2, a1));
        o.z = h2bits(__hmul2(dn2, a2));
        o.w = h2bits(__hmul2(dn2, a3));
        *(uint4*)(aggth + (size_t)n * HID + sub * 8) = o;
    }
}

// layer-3 aggregation + log_softmax: pure sum of pre-scaled h3'.
__global__ __launch_bounds__(256) void k_agg3lsm(const int* __restrict__ rp,
                                                 const int* __restrict__ perm,
                                                 const float* __restrict__ dinv,
                                                 const float2* __restrict__ h3,
                                                 const float2* __restrict__ y3,
                                                 float* __restrict__ out, int N) {
    int n = (blockIdx.x * 256 + threadIdx.x) >> 4;
    if (n >= N) return;
    int sl = threadIdx.x & 15;
    int beg = rp[n], end = rp[n + 1];
    float a0 = 0.0f, a1 = 0.0f;
    for (int j = beg + sl; j < end; j += 16) {
        int s = perm[j];
        float2 hh = h3[s];
        a0 += hh.x;
        a1 += hh.y;
    }
#pragma unroll
    for (int mk = 1; mk <= 8; mk <<= 1) {
        a0 += __shfl_xor(a0, mk);
        a1 += __shfl_xor(a1, mk);
    }
    if (sl == 0) {
        float dn = dinv[n];
        float2 yy = y3[n];
        float z0 = dn * a0 + yy.x;
        float z1 = dn * a1 + yy.y;
        float m = fmaxf(z0, z1);
        float l = m + logf(expf(z0 - m) + expf(z1 - m));
        out[n * 2 + 0] = z0 - l;
        out[n * 2 + 1] = z1 - l;
    }
}

// ---------------- fused dense 2+3 via MFMA ----------------

// T = relu(aggth @ W2 + th @ V2 + b2) in D fragments; layer-3 epilogue writes
// h3' = dinv[n] * (t @ W3)  and  y3 = t @ V3 + b3.
__global__ __launch_bounds__(256) void k_dense23m(
        const unsigned short* __restrict__ aggth, const unsigned short* __restrict__ th,
        const float* __restrict__ W, const float* __restrict__ V,
        const float* __restrict__ b, const float* __restrict__ W3,
        const float* __restrict__ V3, const float* __restrict__ b3,
        const float* __restrict__ dinv,
        float2* __restrict__ h3, float2* __restrict__ y3, int N) {
    __shared__ _Float16 sX[64 * XPITCH];    // [node][K]  K: 0..63 aggth, 64..127 th
    __shared__ _Float16 sWT[64 * XPITCH];   // [feat][K]  K: 0..63 W2,   64..127 V2
    __shared__ float sB2[64];
    __shared__ float sW3[128], sV3[128];
    int tid = threadIdx.x;
    int base = blockIdx.x * 64;
    {
        int f = tid & 63;
        int g = tid >> 6;                      // 0..3
        const float* Wsrc = (g < 2) ? W : V;
        int kbase = (g & 1) * 32;
        int Kbase = (g < 2) ? kbase : (64 + kbase);
#pragma unroll
        for (int k2 = 0; k2 < 32; k2 += 2) {
            float w0 = Wsrc[(kbase + k2) * 64 + f];
            float w1 = Wsrc[(kbase + k2 + 1) * 64 + f];
            __half2 h = __floats2half2_rn(w0, w1);
            *(unsigned int*)&sWT[f * XPITCH + Kbase + k2] = h2bits(h);
        }
        if (tid < 64) sB2[tid] = b[tid];
        if (tid < 128) { sW3[tid] = W3[tid]; sV3[tid] = V3[tid]; }
    }
    {
        int n = tid >> 2, p = tid & 3;
        int g = base + n;
        uint4 z = make_uint4(0, 0, 0, 0);
        uint4 a0 = z, a1 = z, c0 = z, c1 = z;
        if (g < N) {
            const uint4* ap = (const uint4*)(aggth + (size_t)g * HID + p * 16);
            const uint4* cp = (const uint4*)(th + (size_t)g * HID + p * 16);
            a0 = ap[0]; a1 = ap[1];
            c0 = cp[0]; c1 = cp[1];
        }
        *(uint4*)&sX[n * XPITCH + p * 16] = a0;
        *(uint4*)&sX[n * XPITCH + p * 16 + 8] = a1;
        *(uint4*)&sX[n * XPITCH + 64 + p * 16] = c0;
        *(uint4*)&sX[n * XPITCH + 64 + p * 16 + 8] = c1;
    }
    __syncthreads();
    int lane = tid & 63;
    int wv = tid >> 6;          // wave id: rows wv*16 .. wv*16+15
    int ml = lane & 15, quad = lane >> 4;
    half8 a[4];
#pragma unroll
    for (int kt = 0; kt < 4; ++kt)
        a[kt] = *(const half8*)&sX[(wv * 16 + ml) * XPITCH + kt * 32 + quad * 8];
    float p0[4] = {}, p1[4] = {}, q0[4] = {}, q1[4] = {};
#pragma unroll
    for (int c = 0; c < 4; ++c) {
        floatx4 acc = {0.0f, 0.0f, 0.0f, 0.0f};
#pragma unroll
        for (int kt = 0; kt < 4; ++kt) {
            half8 bf = *(const half8*)&sWT[(c * 16 + ml) * XPITCH + kt * 32 + quad * 8];
            acc = __builtin_amdgcn_mfma_f32_16x16x32_f16(a[kt], bf, acc, 0, 0, 0);
        }
        int col = c * 16 + ml;
        float bias = sB2[col];
        float w30 = sW3[col * 2], w31 = sW3[col * 2 + 1];
        float v30 = sV3[col * 2], v31 = sV3[col * 2 + 1];
#pragma unroll
        for (int r = 0; r < 4; ++r) {
            float t = fmaxf(acc[r] + bias, 0.0f);
            p0[r] += t * w30; p1[r] += t * w31;
            q0[r] += t * v30; q1[r] += t * v31;
        }
    }
#pragma unroll
    for (int mk = 1; mk <= 8; mk <<= 1) {
#pragma unroll
        for (int r = 0; r < 4; ++r) {
            p0[r] += __shfl_xor(p0[r], mk);
            p1[r] += __shfl_xor(p1[r], mk);
            q0[r] += __shfl_xor(q0[r], mk);
            q1[r] += __shfl_xor(q1[r], mk);
        }
    }
    if (ml == 0) {
        float b30 = b3[0], b31 = b3[1];
#pragma unroll
        for (int r = 0; r < 4; ++r) {
            int g = base + wv * 16 + quad * 4 + r;
            if (g < N) {
                float dv = dinv[g];
                h3[g] = make_float2(dv * p0[r], dv * p1[r]);
                y3[g] = make_float2(q0[r] + b30, q1[r] + b31);
            }
        }
    }
}

// ---------------- launch ----------------

extern "C" void kernel_launch(void* const* d_in, const int* in_sizes, int n_in,
                              void* d_out, int out_size, void* d_ws, size_t ws_size,
                              hipStream_t stream) {
    const float* x  = (const float*)d_in[0];
    const int*   ei = (const int*)d_in[1];
    const int*   src = ei;
    const int*   dst = ei + NE;
    const float* W1 = (const float*)d_in[2];
    const float* V1 = (const float*)d_in[3];
    const float* b1 = (const float*)d_in[4];
    const float* W2 = (const float*)d_in[5];
    const float* V2 = (const float*)d_in[6];
    const float* b2 = (const float*)d_in[7];
    const float* W3 = (const float*)d_in[8];
    const float* V3 = (const float*)d_in[9];
    const float* b3 = (const float*)d_in[10];
    float* out = (float*)d_out;

    // workspace layout (float offsets) — ws_size = 256 MiB (poison-fill WRITE_SIZE),
    // usage ends at 18,934,848 floats = 75.7 MB.
    float* ws = (float*)d_ws;
    int*   bcur1 = (int*)ws;                          // 49*32 (region 2048)
    int*   bcur2 = (int*)(ws + 2048);                 // 782*32 = 25024
    int*   ebase = (int*)(ws + 27136);                // NBUCK+1
    int*   rp    = (int*)(ws + 28160);                // NN+1
    float* dinv  = ws + 128512;                       // NN -> 228864
    // S region: sbdata (binA1->binA2), then perm (binB -> end)
    unsigned int* sbdata = (unsigned int*)(ws + 228864);   // 49*34816 -> 1,934,848
    int*   perm  = (int*)(ws + 228864);                    // NE (aliases sbdata)
    // T region: fbdata (binA2->binB), then h3/y3 (dense23m -> agg3lsm)
    unsigned int* fbdata = (unsigned int*)(ws + 1934848);  // 782*2304 -> 3,736,576
    float2* h3   = (float2*)(ws + 1934848);                // NN float2
    float2* y3   = (float2*)(ws + 1934848 + 2 * NN);       // NN float2
    // A region — DISJOINT fp16 arrays (R15 bug: th2/y overlapped aggth)
    unsigned short* aggth = (unsigned short*)(ws + 8334848);  // NN*64 fp16 -> 11,534,848
    unsigned short* th2   = (unsigned short*)(ws + 11534848); // NN*64 fp16 -> 14,734,848
    unsigned short* th    = (unsigned short*)(ws + 14734848); // NN*64 fp16 -> 17,934,848
    float* y              = ws + 17934848;                    // NN*10 -> 18,934,848

    const int B = 256;

    // ---- CSR build: two-level multisplit (+ dinv + y) ----
    hipMemsetAsync(bcur1, 0, 27072 * sizeof(int), stream);  // bcur1+bcur2 contiguous
    k_binA1<<<NBLK1, B, 0, stream>>>(src, dst, bcur1, sbdata);
    k_binA2<<<NSB * NSLICE, B, 0, stream>>>(bcur1, sbdata, bcur2, fbdata);
    k_bscan<<<1, 1024, 0, stream>>>(bcur2, ebase);
    k_binB<<<NBUCK, B, 0, stream>>>(bcur2, ebase, fbdata, rp, dinv, perm, x, y);

    // ---- layer 1 (fused gather + dense) -> fp16 th, th2 ----
    k_l1f<<<(NN * 16 + B - 1) / B, B, 0, stream>>>(rp, perm, dinv, x, y,
                                                   W1, V1, b1, th, th2, NN);

    // ---- layer 2: pure-sum gather, then MFMA dense2+3 ----
    k_agg64h<<<(NN * 64 + B - 1) / B, B, 0, stream>>>(rp, perm, dinv, th2, aggth, NN);
    k_dense23m<<<(NN + 63) / 64, B, 0, stream>>>(aggth, th, W2, V2, b2, W3, V3, b3,
                                                 dinv, h3, y3, NN);

    // ---- layer 3 aggregate + log_softmax ----
    k_agg3lsm<<<(NN * 16 + B - 1) / B, B, 0, stream>>>(rp, perm, dinv,
                                                       (const float2*)h3,
                                                       (const float2*)y3, out, NN);
}

// Round 18
// 207.233 us; speedup vs baseline: 1.0852x; 1.0245x over previous
//
#include <hip/hip_runtime.h>
#include <hip/hip_fp16.h>
#include <math.h>

#define NN 100000
#define NE 1600000
#define HID 64
// fine buckets (binB granularity)
#define BN 128
#define NBUCK 782          // ceil(NN/128)
#define FBCAP 2304         // fine bucket capacity (mean 2048, +5.7 sigma)
// coarse superbuckets (binA granularity)
#define NSB 49             // ceil(NN/2048)
#define SBCAP 34816        // superbucket capacity (mean 32653, +12 sigma)
#define CHUNK1 4096
#define NBLK1 391          // ceil(NE/4096)
#define NSLICE 16          // binA2 slices per superbucket
#define SLCAP 2304         // >= ceil(SBCAP/16) = 2176
#define CSTRIDE 32         // ints between cursors (128 B)
#define XPITCH 136         // LDS row pitch in halfs (128 + 8; 272 B, 16B-aligned rows)

typedef _Float16 half8 __attribute__((ext_vector_type(8)));
typedef float floatx4 __attribute__((ext_vector_type(4)));

__device__ __forceinline__ __half2 shfl_xor_h2(__half2 v, int m) {
    unsigned int u = *(unsigned int*)&v;
    u = __shfl_xor(u, m);
    return *(__half2*)&u;
}
__device__ __forceinline__ unsigned int h2bits(__half2 v) {
    return *(unsigned int*)&v;
}

// ---------------- CSR build: two-level multisplit ----------------

// Pass A1: multisplit edges into 49 superbuckets (dst>>11). 4096-edge chunks.
// Packed u32: src (17b) | (dst & 2047) << 17.
__global__ __launch_bounds__(256) void k_binA1(const int* __restrict__ src,
                                               const int* __restrict__ dst,
                                               int* __restrict__ bcur1,
                                               unsigned int* __restrict__ sbdata) {
    __shared__ unsigned int par[CHUNK1];
    __shared__ unsigned short rnk[CHUNK1];
    __shared__ unsigned char bkt[CHUNK1];
    __shared__ int hist[NSB];
    __shared__ int base[NSB];
    int tid = threadIdx.x;
    int e0 = blockIdx.x * CHUNK1;
    int m = NE - e0; if (m > CHUNK1) m = CHUNK1;
    if (tid < NSB) hist[tid] = 0;
    __syncthreads();
    for (int i = tid; i < m; i += 256) {
        int s = src[e0 + i], d = dst[e0 + i];
        int b = d >> 11;
        par[i] = (unsigned int)s | ((unsigned int)(d & 2047) << 17);
        bkt[i] = (unsigned char)b;
        rnk[i] = (unsigned short)atomicAdd(&hist[b], 1);
    }
    __syncthreads();
    if (tid < NSB) {
        int h = hist[tid];
        base[tid] = h ? atomicAdd(&bcur1[tid * CSTRIDE], h) : 0;
    }
    __syncthreads();
    for (int i = tid; i < m; i += 256) {
        int b = bkt[i];
        int pos = base[b] + rnk[i];
        if (pos < SBCAP) sbdata[(size_t)b * SBCAP + pos] = par[i];
    }
}

// Pass A2: split each superbucket into its 16 fine buckets (16 slices each).
// Output u32: src (17b) | dlocal(7b) << 17.
__global__ __launch_bounds__(256) void k_binA2(const int* __restrict__ bcur1,
                                               const unsigned int* __restrict__ sbdata,
                                               int* __restrict__ bcur2,
                                               unsigned int* __restrict__ fbdata) {
    __shared__ unsigned int par[SLCAP];
    __shared__ unsigned short rnk[SLCAP];
    __shared__ unsigned char bkt[SLCAP];
    __shared__ int hist[16];
    __shared__ int base[16];
    int tid = threadIdx.x;
    int sb = blockIdx.x >> 4, sl = blockIdx.x & 15;
    int m = bcur1[sb * CSTRIDE]; if (m > SBCAP) m = SBCAP;
    int L = (m + NSLICE - 1) >> 4;
    int lo = sl * L;
    int cnt = m - lo; if (cnt > L) cnt = L; if (cnt < 0) cnt = 0;
    if (tid < 16) hist[tid] = 0;
    __syncthreads();
    const unsigned int* sp = sbdata + (size_t)sb * SBCAP + lo;
    for (int i = tid; i < cnt; i += 256) {
        unsigned int u = sp[i];
        int dlow = (u >> 17) & 2047;
        int f = dlow >> 7;
        par[i] = (u & 0x1ffffu) | ((unsigned int)(dlow & 127) << 17);
        bkt[i] = (unsigned char)f;
        rnk[i] = (unsigned short)atomicAdd(&hist[f], 1);
    }
    __syncthreads();
    if (tid < 16) {
        int h = hist[tid];
        base[tid] = h ? atomicAdd(&bcur2[(sb * 16 + tid) * CSTRIDE], h) : 0;
    }
    __syncthreads();
    for (int i = tid; i < cnt; i += 256) {
        int f = bkt[i];
        int pos = base[f] + rnk[i];
        if (pos < FBCAP) fbdata[(size_t)(sb * 16 + f) * FBCAP + pos] = par[i];
    }
}

// exclusive scan of fine-bucket totals — wave-level scan (2 barriers).
__global__ void k_bscan(const int* __restrict__ bcur2, int* __restrict__ ebase) {
    __shared__ int ls[16];
    int t = threadIdx.x;
    int lane = t & 63, wid = t >> 6;
    int v = 0;
    if (t < NBUCK) {
        int m = bcur2[t * CSTRIDE];
        v = (m < FBCAP) ? m : FBCAP;
    }
    int orig = v;
    for (int off = 1; off < 64; off <<= 1) {
        int u = __shfl_up(v, off);
        if (lane >= off) v += u;
    }
    if (lane == 63) ls[wid] = v;
    __syncthreads();
    if (wid == 0) {
        int w = (lane < 16) ? ls[lane] : 0;
        for (int off = 1; off < 16; off <<= 1) {
            int u = __shfl_up(w, off);
            if (lane >= off) w += u;
        }
        if (lane < 16) ls[lane] = w;
    }
    __syncthreads();
    int base = wid ? ls[wid - 1] : 0;
    int incl = base + v;
    if (t < NBUCK) ebase[t] = incl - orig;
    if (t == NBUCK - 1) ebase[NBUCK] = incl;  // = NE
}

// Pass B: per fine bucket (256 threads) — single-pass stage+rank, shfl scan,
// atomic-free scatter of perm, dinv, and yh = fp16(dinv * x) for owned nodes.
__global__ __launch_bounds__(256) void k_binB(const int* __restrict__ bcur2,
                                              const int* __restrict__ ebase,
                                              const unsigned int* __restrict__ fbdata,
                                              int* __restrict__ rp, float* __restrict__ dinv,
                                              int* __restrict__ perm,
                                              const float* __restrict__ x,
                                              unsigned short* __restrict__ yh) {
    __shared__ unsigned int se[FBCAP];      // 9.2 KB
    __shared__ unsigned short rnk[FBCAP];   // 4.6 KB
    __shared__ int cnt[BN];
    __shared__ int ex[BN];
    __shared__ float sdv[BN];
    __shared__ int wsum[2];
    int b = blockIdx.x, tid = threadIdx.x;
    int m = bcur2[b * CSTRIDE]; if (m > FBCAP) m = FBCAP;
    int base = ebase[b];
    if (tid < BN) cnt[tid] = 0;
    __syncthreads();
    // stage + rank in one pass
    for (int i = tid; i < m; i += 256) {
        unsigned int u = fbdata[(size_t)b * FBCAP + i];
        se[i] = u;
        rnk[i] = (unsigned short)atomicAdd(&cnt[u >> 17], 1);
    }
    __syncthreads();
    // shfl scan over 128 counts (waves 0,1)
    if (tid < BN) {
        int c = cnt[tid];
        int v = c;
        int lane = tid & 63;
        for (int off = 1; off < 64; off <<= 1) {
            int u = __shfl_up(v, off);
            if (lane >= off) v += u;
        }
        if (lane == 63) wsum[tid >> 6] = v;
        int g = b * BN + tid;
        float dv = (c > 0) ? rsqrtf((float)c) : 0.0f;
        sdv[tid] = dv;
        if (g < NN) dinv[g] = dv;
        cnt[tid] = v - c;   // exclusive within wave
    }
    __syncthreads();
    if (tid < BN) {
        int excl = cnt[tid] + ((tid >= 64) ? wsum[0] : 0);
        ex[tid] = excl;
        int g = b * BN + tid;
        if (g < NN) rp[g] = base + excl;
    }
    if (b == NBUCK - 1 && tid == 0) rp[NN] = ebase[NBUCK];
    __syncthreads();
    // atomic-free scatter
    for (int i = tid; i < m; i += 256) {
        unsigned int u = se[i];
        int dl = u >> 17;
        perm[base + ex[dl] + rnk[i]] = (int)(u & 0x1ffffu);
    }
    // yh = fp16(dinv * x) for owned nodes
    {
        int nbase = b * BN;
        int lim = NN - nbase; if (lim > BN) lim = BN;
        int tot = lim * 10;
        for (int idx = tid; idx < tot; idx += 256) {
            int nl = idx / 10;
            int k = idx - nl * 10;
            float v = sdv[nl] * x[(size_t)(nbase + nl) * 10 + k];
            yh[(size_t)(nbase + nl) * 10 + k] = (unsigned short)__half_as_ushort(__float2half_rn(v));
        }
    }
}

// ---------------- layer 1 fused: aggregate yh + dense1 -> fp16 th, th2 ----------------

// 16 lanes per node. agg = dinv[n] * sum_s yh[s] (yh pre-scaled by dinv[s],
// fp16 rows of 20 B from a 2 MB L2-resident array).
__global__ __launch_bounds__(256) void k_l1f(
        const int* __restrict__ rp, const int* __restrict__ perm,
        const float* __restrict__ dinv, const float* __restrict__ x,
        const unsigned short* __restrict__ yh,
        const float* __restrict__ W, const float* __restrict__ V,
        const float* __restrict__ b, unsigned short* __restrict__ th,
        unsigned short* __restrict__ th2, int N) {
    __shared__ float sW[640], sV[640];
    for (int i = threadIdx.x; i < 640; i += 256) { sW[i] = W[i]; sV[i] = V[i]; }
    __syncthreads();
    int n = (blockIdx.x * 256 + threadIdx.x) >> 4;
    if (n >= N) return;
    int sub = threadIdx.x & 15;
    int beg = rp[n], end = rp[n + 1];
    float ag[10];
#pragma unroll
    for (int k = 0; k < 10; ++k) ag[k] = 0.0f;
    for (int j = beg + sub; j < end; j += 16) {
        int s = perm[j];
        const unsigned int* yr = (const unsigned int*)(yh + (size_t)s * 10);
        unsigned int u0 = yr[0], u1 = yr[1], u2 = yr[2], u3 = yr[3], u4 = yr[4];
        float2 v0 = __half22float2(*(__half2*)&u0);
        float2 v1 = __half22float2(*(__half2*)&u1);
        float2 v2 = __half22float2(*(__half2*)&u2);
        float2 v3 = __half22float2(*(__half2*)&u3);
        float2 v4 = __half22float2(*(__half2*)&u4);
        ag[0] += v0.x; ag[1] += v0.y; ag[2] += v1.x; ag[3] += v1.y;
        ag[4] += v2.x; ag[5] += v2.y; ag[6] += v3.x; ag[7] += v3.y;
        ag[8] += v4.x; ag[9] += v4.y;
    }
#pragma unroll
    for (int mk = 1; mk <= 8; mk <<= 1) {
#pragma unroll
        for (int k = 0; k < 10; ++k) ag[k] += __shfl_xor(ag[k], mk);
    }
    float dn = dinv[n];
#pragma unroll
    for (int k = 0; k < 10; ++k) ag[k] *= dn;
    const float2* xn = (const float2*)(x + (size_t)n * 10);
    float2 x0 = xn[0], x1 = xn[1], x2 = xn[2], x3 = xn[3], x4 = xn[4];
    float xv[10] = {x0.x, x0.y, x1.x, x1.y, x2.x, x2.y, x3.x, x3.y, x4.x, x4.y};
    int f0 = sub * 4;
    float4 bb = *(const float4*)(b + f0);
    float acc[4] = {bb.x, bb.y, bb.z, bb.w};
#pragma unroll
    for (int k = 0; k < 10; ++k) {
        float4 wq = *(const float4*)&sW[k * HID + f0];
        float4 vq = *(const float4*)&sV[k * HID + f0];
        acc[0] += ag[k] * wq.x + xv[k] * vq.x;
        acc[1] += ag[k] * wq.y + xv[k] * vq.y;
        acc[2] += ag[k] * wq.z + xv[k] * vq.z;
        acc[3] += ag[k] * wq.w + xv[k] * vq.w;
    }
    float t0 = fmaxf(acc[0], 0.0f), t1 = fmaxf(acc[1], 0.0f);
    float t2 = fmaxf(acc[2], 0.0f), t3 = fmaxf(acc[3], 0.0f);
    __half2 lo = __floats2half2_rn(t0, t1);
    __half2 hi = __floats2half2_rn(t2, t3);
    *(uint2*)(th + (size_t)n * HID + f0) = make_uint2(h2bits(lo), h2bits(hi));
    __half2 lo2 = __floats2half2_rn(dn * t0, dn * t1);
    __half2 hi2 = __floats2half2_rn(dn * t2, dn * t3);
    *(uint2*)(th2 + (size_t)n * HID + f0) = make_uint2(h2bits(lo2), h2bits(hi2));
}

// ---------------- layer-2 aggregation: pure row sum of th2 ----------------

// aggth[n] = fp16(dinv[n] * sum_s th2[s]). Wave per node: 8 groups x 8 lanes,
// 2 edges unrolled -> 16 independent 128 B lines in flight per wave.
__global__ __launch_bounds__(256) void k_agg64h(
        const int* __restrict__ rp, const int* __restrict__ perm,
        const float* __restrict__ dinv, const unsigned short* __restrict__ th2,
        unsigned short* __restrict__ aggth, int N) {
    int wid = (blockIdx.x * blockDim.x + threadIdx.x) >> 6;
    if (wid >= N) return;
    int n = __builtin_amdgcn_readfirstlane(wid);
    int lane = threadIdx.x & 63;
    int grp = lane >> 3;
    int sub = lane & 7;
    int beg = rp[n], end = rp[n + 1];
    __half2 a0 = __float2half2_rn(0.0f), a1 = a0, a2 = a0, a3 = a0;
    int j = beg + grp;
    for (; j + 8 < end; j += 16) {
        int sa = perm[j], sb = perm[j + 8];
        uint4 ua = *(const uint4*)(th2 + (size_t)sa * HID + sub * 8);
        uint4 ub = *(const uint4*)(th2 + (size_t)sb * HID + sub * 8);
        a0 = __hadd2(a0, __hadd2(*(__half2*)&ua.x, *(__half2*)&ub.x));
        a1 = __hadd2(a1, __hadd2(*(__half2*)&ua.y, *(__half2*)&ub.y));
        a2 = __hadd2(a2, __hadd2(*(__half2*)&ua.z, *(__half2*)&ub.z));
        a3 = __hadd2(a3, __hadd2(*(__half2*)&ua.w, *(__half2*)&ub.w));
    }
    if (j < end) {
        int sa = perm[j];
        uint4 ua = *(const uint4*)(th2 + (size_t)sa * HID + sub * 8);
        a0 = __hadd2(a0, *(__half2*)&ua.x);
        a1 = __hadd2(a1, *(__half2*)&ua.y);
        a2 = __hadd2(a2, *(__half2*)&ua.z);
        a3 = __hadd2(a3, *(__half2*)&ua.w);
    }
#pragma unroll
    for (int m = 8; m < 64; m <<= 1) {
        a0 = __hadd2(a0, shfl_xor_h2(a0, m));
        a1 = __hadd2(a1, shfl_xor_h2(a1, m));
        a2 = __hadd2(a2, shfl_xor_h2(a2, m));
        a3 = __hadd2(a3, shfl_xor_h2(a3, m));
    }
    if (grp == 0) {
        __half2 dn2 = __float2half2_rn(dinv[n]);
        uint4 o;
        o.x = h2bits(__hmul2(dn2, a0));
        o.y = h2bits(__hmul2(dn2, a1));
        o.z = h2bits(__hmul2(dn2, a2));
        o.w = h2bits(__hmul2(dn2, a3));
        *(uint4*)(aggth + (size_t)n * HID + sub * 8) = o;
    }
}

// layer-3 aggregation + log_softmax: pure sum of pre-scaled packed-fp16 h3'.
__global__ __launch_bounds__(256) void k_agg3lsm(const int* __restrict__ rp,
                                                 const int* __restrict__ perm,
                                                 const float* __restrict__ dinv,
                                                 const unsigned int* __restrict__ h3h,
                                                 const float2* __restrict__ y3,
                                                 float* __restrict__ out, int N) {
    int n = (blockIdx.x * 256 + threadIdx.x) >> 4;
    if (n >= N) return;
    int sl = threadIdx.x & 15;
    int beg = rp[n], end = rp[n + 1];
    float a0 = 0.0f, a1 = 0.0f;
    for (int j = beg + sl; j < end; j += 16) {
        int s = perm[j];
        unsigned int u = h3h[s];
        float2 hh = __half22float2(*(__half2*)&u);
        a0 += hh.x;
        a1 += hh.y;
    }
#pragma unroll
    for (int mk = 1; mk <= 8; mk <<= 1) {
        a0 += __shfl_xor(a0, mk);
        a1 += __shfl_xor(a1, mk);
    }
    if (sl == 0) {
        float dn = dinv[n];
        float2 yy = y3[n];
        float z0 = dn * a0 + yy.x;
        float z1 = dn * a1 + yy.y;
        float m = fmaxf(z0, z1);
        float l = m + logf(expf(z0 - m) + expf(z1 - m));
        out[n * 2 + 0] = z0 - l;
        out[n * 2 + 1] = z1 - l;
    }
}

// ---------------- fused dense 2+3 via MFMA ----------------

// T = relu(aggth @ W2 + th @ V2 + b2) in D fragments; layer-3 epilogue writes
// h3h = fp16x2(dinv[n] * (t @ W3))  and  y3 = t @ V3 + b3.
__global__ __launch_bounds__(256) void k_dense23m(
        const unsigned short* __restrict__ aggth, const unsigned short* __restrict__ th,
        const float* __restrict__ W, const float* __restrict__ V,
        const float* __restrict__ b, const float* __restrict__ W3,
        const float* __restrict__ V3, const float* __restrict__ b3,
        const float* __restrict__ dinv,
        unsigned int* __restrict__ h3h, float2* __restrict__ y3, int N) {
    __shared__ _Float16 sX[64 * XPITCH];    // [node][K]  K: 0..63 aggth, 64..127 th
    __shared__ _Float16 sWT[64 * XPITCH];   // [feat][K]  K: 0..63 W2,   64..127 V2
    __shared__ float sB2[64];
    __shared__ float sW3[128], sV3[128];
    int tid = threadIdx.x;
    int base = blockIdx.x * 64;
    {
        int f = tid & 63;
        int g = tid >> 6;                      // 0..3
        const float* Wsrc = (g < 2) ? W : V;
        int kbase = (g & 1) * 32;
        int Kbase = (g < 2) ? kbase : (64 + kbase);
#pragma unroll
        for (int k2 = 0; k2 < 32; k2 += 2) {
            float w0 = Wsrc[(kbase + k2) * 64 + f];
            float w1 = Wsrc[(kbase + k2 + 1) * 64 + f];
            __half2 h = __floats2half2_rn(w0, w1);
            *(unsigned int*)&sWT[f * XPITCH + Kbase + k2] = h2bits(h);
        }
        if (tid < 64) sB2[tid] = b[tid];
        if (tid < 128) { sW3[tid] = W3[tid]; sV3[tid] = V3[tid]; }
    }
    {
        int n = tid >> 2, p = tid & 3;
        int g = base + n;
        uint4 z = make_uint4(0, 0, 0, 0);
        uint4 a0 = z, a1 = z, c0 = z, c1 = z;
        if (g < N) {
            const uint4* ap = (const uint4*)(aggth + (size_t)g * HID + p * 16);
            const uint4* cp = (const uint4*)(th + (size_t)g * HID + p * 16);
            a0 = ap[0]; a1 = ap[1];
            c0 = cp[0]; c1 = cp[1];
        }
        *(uint4*)&sX[n * XPITCH + p * 16] = a0;
        *(uint4*)&sX[n * XPITCH + p * 16 + 8] = a1;
        *(uint4*)&sX[n * XPITCH + 64 + p * 16] = c0;
        *(uint4*)&sX[n * XPITCH + 64 + p * 16 + 8] = c1;
    }
    __syncthreads();
    int lane = tid & 63;
    int wv = tid >> 6;          // wave id: rows wv*16 .. wv*16+15
    int ml = lane & 15, quad = lane >> 4;
    half8 a[4];
#pragma unroll
    for (int kt = 0; kt < 4; ++kt)
        a[kt] = *(const half8*)&sX[(wv * 16 + ml) * XPITCH + kt * 32 + quad * 8];
    float p0[4] = {}, p1[4] = {}, q0[4] = {}, q1[4] = {};
#pragma unroll
    for (int c = 0; c < 4; ++c) {
        floatx4 acc = {0.0f, 0.0f, 0.0f, 0.0f};
#pragma unroll
        for (int kt = 0; kt < 4; ++kt) {
            half8 bf = *(const half8*)&sWT[(c * 16 + ml) * XPITCH + kt * 32 + quad * 8];
            acc = __builtin_amdgcn_mfma_f32_16x16x32_f16(a[kt], bf, acc, 0, 0, 0);
        }
        int col = c * 16 + ml;
        float bias = sB2[col];
        float w30 = sW3[col * 2], w31 = sW3[col * 2 + 1];
        float v30 = sV3[col * 2], v31 = sV3[col * 2 + 1];
#pragma unroll
        for (int r = 0; r < 4; ++r) {
            float t = fmaxf(acc[r] + bias, 0.0f);
            p0[r] += t * w30; p1[r] += t * w31;
            q0[r] += t * v30; q1[r] += t * v31;
        }
    }
#pragma unroll
    for (int mk = 1; mk <= 8; mk <<= 1) {
#pragma unroll
        for (int r = 0; r < 4; ++r) {
            p0[r] += __shfl_xor(p0[r], mk);
            p1[r] += __shfl_xor(p1[r], mk);
            q0[r] += __shfl_xor(q0[r], mk);
            q1[r] += __shfl_xor(q1[r], mk);
        }
    }
    if (ml == 0) {
        float b30 = b3[0], b31 = b3[1];
#pragma unroll
        for (int r = 0; r < 4; ++r) {
            int g = base + wv * 16 + quad * 4 + r;
            if (g < N) {
                float dv = dinv[g];
                h3h[g] = h2bits(__floats2half2_rn(dv * p0[r], dv * p1[r]));
                y3[g] = make_float2(q0[r] + b30, q1[r] + b31);
            }
        }
    }
}

// ---------------- launch ----------------

extern "C" void kernel_launch(void* const* d_in, const int* in_sizes, int n_in,
                              void* d_out, int out_size, void* d_ws, size_t ws_size,
                              hipStream_t stream) {
    const float* x  = (const float*)d_in[0];
    const int*   ei = (const int*)d_in[1];
    const int*   src = ei;
    const int*   dst = ei + NE;
    const float* W1 = (const float*)d_in[2];
    const float* V1 = (const float*)d_in[3];
    const float* b1 = (const float*)d_in[4];
    const float* W2 = (const float*)d_in[5];
    const float* V2 = (const float*)d_in[6];
    const float* b2 = (const float*)d_in[7];
    const float* W3 = (const float*)d_in[8];
    const float* V3 = (const float*)d_in[9];
    const float* b3 = (const float*)d_in[10];
    float* out = (float*)d_out;

    // workspace layout (float offsets) — all regions disjoint; ends 18,434,848 floats.
    float* ws = (float*)d_ws;
    int*   bcur1 = (int*)ws;                          // 49*32 (region 2048)
    int*   bcur2 = (int*)(ws + 2048);                 // 782*32 = 25024
    int*   ebase = (int*)(ws + 27136);                // NBUCK+1
    int*   rp    = (int*)(ws + 28160);                // NN+1
    float* dinv  = ws + 128512;                       // NN -> 228864
    // S region: sbdata (binA1->binA2), then perm (binB -> end)
    unsigned int* sbdata = (unsigned int*)(ws + 228864);   // 49*34816 -> 1,934,848
    int*   perm  = (int*)(ws + 228864);                    // NE (aliases sbdata)
    // T region: fbdata (binA2->binB), then h3h/y3 (dense23m -> agg3lsm)
    unsigned int* fbdata = (unsigned int*)(ws + 1934848);  // 782*2304 -> 3,736,576
    unsigned int* h3h = (unsigned int*)(ws + 1934848);     // NN u32
    float2* y3   = (float2*)(ws + 1934848 + NN);           // NN float2 -> ends 2,234,848
    // A region — disjoint fp16 arrays
    unsigned short* aggth = (unsigned short*)(ws + 8334848);  // NN*64 fp16 -> 11,534,848
    unsigned short* th2   = (unsigned short*)(ws + 11534848); // NN*64 fp16 -> 14,734,848
    unsigned short* th    = (unsigned short*)(ws + 14734848); // NN*64 fp16 -> 17,934,848
    unsigned short* yh    = (unsigned short*)(ws + 17934848); // NN*10 fp16 -> 18,434,848

    const int B = 256;

    // ---- CSR build: two-level multisplit (+ dinv + yh) ----
    hipMemsetAsync(bcur1, 0, 27072 * sizeof(int), stream);  // bcur1+bcur2 contiguous
    k_binA1<<<NBLK1, B, 0, stream>>>(src, dst, bcur1, sbdata);
    k_binA2<<<NSB * NSLICE, B, 0, stream>>>(bcur1, sbdata, bcur2, fbdata);
    k_bscan<<<1, 1024, 0, stream>>>(bcur2, ebase);
    k_binB<<<NBUCK, B, 0, stream>>>(bcur2, ebase, fbdata, rp, dinv, perm, x, yh);

    // ---- layer 1 (fused gather + dense) -> fp16 th, th2 ----
    k_l1f<<<(NN * 16 + B - 1) / B, B, 0, stream>>>(rp, perm, dinv, x, yh,
                                                   W1, V1, b1, th, th2, NN);

    // ---- layer 2: pure-sum gather, then MFMA dense2+3 ----
    k_agg64h<<<(NN * 64 + B - 1) / B, B, 0, stream>>>(rp, perm, dinv, th2, aggth, NN);
    k_dense23m<<<(NN + 63) / 64, B, 0, stream>>>(aggth, th, W2, V2, b2, W3, V3, b3,
                                                 dinv, h3h, y3, NN);

    // ---- layer 3 aggregate + log_softmax ----
    k_agg3lsm<<<(NN * 16 + B - 1) / B, B, 0, stream>>>(rp, perm, dinv, h3h,
                                                       (const float2*)y3, out, NN);
}